// Round 1
// baseline (98.320 us; speedup 1.0000x reference)
//
#include <hip/hip_runtime.h>
#include <hip/hip_bf16.h>

// PointerNetwork: scores[b,d,e] = sum_h v[h]*tanh(dec_t[b,d,h] + enc_t[b,e,h]),
// out = log_softmax(scores, axis=e).  B=4, DEC=256, ENC=1024, H=256, fp32.
//
// Plan:
//   K1 (gemm_abt): enc_tT[b][h][e] = SC * (x_enc[b,e,:] . w1[h,:])   (transposed, pre-scaled)
//                  decS[b][d][h]   = SC * (x_dec[b,d,:] . w2[h,:])
//                  where SC = 2*log2(e), so exp(2x) == exp2(encT+decS).
//   K2 (scores_lsm): per (b, 4 d-rows) block: lane-per-e h-loop with
//                  tanh via 1 - 2*rcp(1+exp2(arg)), then block log_softmax.

#define B_ 4
#define DEC_ 256
#define ENC_ 1024
#define H_ 256

// ---------------- Kernel 1: fused dual GEMM (A . B^T) * scale ----------------
// Tiles: TM=TN=64, TK=32, 256 threads, 4x4 micro-tile per thread.
// blocks 0..255  : enc  (A=w1 [h][k], B=x_enc[b] [e][k], C=encT[b] [h][e], ldc=1024)
// blocks 256..319: dec  (A=x_dec[b] [d][k], B=w2 [h][k], C=decS[b] [d][h], ldc=256)

#define TM 64
#define TN 64
#define TK 32
#define LDP 68   // padded LDS leading dim (68 mod 32 = 4 -> breaks write conflicts, keeps 16B align)

__global__ __launch_bounds__(256) void gemm_abt(
    const float* __restrict__ w1, const float* __restrict__ xe,
    const float* __restrict__ xd, const float* __restrict__ w2,
    float* __restrict__ encT, float* __restrict__ decS) {
  const int blk = blockIdx.x;
  const float* A;
  const float* Bm;
  float* C;
  int ldc, tM, tN;
  if (blk < 256) {
    const int b = blk >> 6;
    const int t = blk & 63;       // 4 (tileM over h) x 16 (tileN over e)
    tM = t >> 4; tN = t & 15;
    A = w1;
    Bm = xe + (size_t)b * ENC_ * H_;
    C = encT + (size_t)b * H_ * ENC_;
    ldc = ENC_;
  } else {
    const int blk2 = blk - 256;
    const int b = blk2 >> 4;
    const int t = blk2 & 15;      // 4 x 4
    tM = t >> 2; tN = t & 3;
    A = xd + (size_t)b * DEC_ * H_;
    Bm = w2;
    C = decS + (size_t)b * DEC_ * H_;
    ldc = H_;
  }
  const int K = H_;

  __shared__ __align__(16) float As[TK][LDP];  // k-major: As[k][m]
  __shared__ __align__(16) float Bs[TK][LDP];

  const int tid = threadIdx.x;
  const int tr = tid >> 4;   // 0..15 -> C rows tr*4..tr*4+3
  const int tc = tid & 15;   // 0..15 -> C cols tc*4..tc*4+3

  float acc[4][4] = {};

  for (int k0 = 0; k0 < K; k0 += TK) {
    const int lrow = tid >> 3;        // 0..31
    const int lk = (tid & 7) << 2;    // 0,4,...,28
#pragma unroll
    for (int s = 0; s < 2; ++s) {
      const int row = lrow + s * 32;
      float4 a4 = *(const float4*)(A + (size_t)(tM * 64 + row) * K + k0 + lk);
      As[lk + 0][row] = a4.x; As[lk + 1][row] = a4.y;
      As[lk + 2][row] = a4.z; As[lk + 3][row] = a4.w;
      float4 b4 = *(const float4*)(Bm + (size_t)(tN * 64 + row) * K + k0 + lk);
      Bs[lk + 0][row] = b4.x; Bs[lk + 1][row] = b4.y;
      Bs[lk + 2][row] = b4.z; Bs[lk + 3][row] = b4.w;
    }
    __syncthreads();
#pragma unroll
    for (int kk = 0; kk < TK; ++kk) {
      float4 a = *(const float4*)&As[kk][tr << 2];
      float4 b = *(const float4*)&Bs[kk][tc << 2];
      acc[0][0] += a.x * b.x; acc[0][1] += a.x * b.y; acc[0][2] += a.x * b.z; acc[0][3] += a.x * b.w;
      acc[1][0] += a.y * b.x; acc[1][1] += a.y * b.y; acc[1][2] += a.y * b.z; acc[1][3] += a.y * b.w;
      acc[2][0] += a.z * b.x; acc[2][1] += a.z * b.y; acc[2][2] += a.z * b.z; acc[2][3] += a.z * b.w;
      acc[3][0] += a.w * b.x; acc[3][1] += a.w * b.y; acc[3][2] += a.w * b.z; acc[3][3] += a.w * b.w;
    }
    __syncthreads();
  }

  const float SC = 2.8853900817779268f;  // 2*log2(e): pre-scale for exp2-based tanh
#pragma unroll
  for (int i = 0; i < 4; ++i) {
    const int row = tM * 64 + (tr << 2) + i;
    float4 o;
    o.x = acc[i][0] * SC; o.y = acc[i][1] * SC;
    o.z = acc[i][2] * SC; o.w = acc[i][3] * SC;
    *(float4*)(C + (size_t)row * ldc + (tN << 6) + (tc << 2)) = o;
  }
}

// ---------------- Kernel 2: scores + log_softmax ----------------
// Block = 512 threads, handles (b, 4 consecutive d). Lane t owns e = t and t+512.
// tanh(x) = 1 - 2*rcp(1 + exp2(argScaled)), argScaled = encT + decS (pre-scaled).
// score = Vsum - sum_h (2 v[h]) * rcp(1 + exp2(...)).

#define DT 4

__global__ __launch_bounds__(512) void scores_lsm(
    const float* __restrict__ encT, const float* __restrict__ decS,
    const float* __restrict__ v, float* __restrict__ out) {
  const int bid = blockIdx.x;
  const int b = bid >> 6;              // 64 d-groups per batch
  const int d0 = (bid & 63) * DT;
  const int tid = threadIdx.x;

  __shared__ float w2v[H_];
  __shared__ float sdec[DT][H_];
  __shared__ float redm[DT][8];
  __shared__ float reds[DT][8];

  if (tid < H_) w2v[tid] = 2.0f * v[tid];
  {
    const int d = tid >> 8;            // 0..1
    const int h = tid & 255;
    sdec[d][h]     = decS[((size_t)(b * DEC_ + d0 + d)) * H_ + h];
    sdec[d + 2][h] = decS[((size_t)(b * DEC_ + d0 + d + 2)) * H_ + h];
  }
  __syncthreads();

  // Vsum = sum_h v[h] (cheap LDS broadcast scan)
  float vs = 0.0f;
#pragma unroll 8
  for (int h = 0; h < H_; ++h) vs += w2v[h];
  const float vsum = 0.5f * vs;

  const float* ep = encT + (size_t)b * H_ * ENC_;
  float acc[DT][2] = {};

  for (int h = 0; h < H_; ++h) {
    const float e0 = ep[(size_t)h * ENC_ + tid];
    const float e1 = ep[(size_t)h * ENC_ + tid + 512];
    const float wv = w2v[h];
#pragma unroll
    for (int d = 0; d < DT; ++d) {
      const float dc = sdec[d][h];
      float y0 = __builtin_amdgcn_exp2f(e0 + dc);
      float r0 = __builtin_amdgcn_rcpf(1.0f + y0);
      acc[d][0] += wv * r0;
      float y1 = __builtin_amdgcn_exp2f(e1 + dc);
      float r1 = __builtin_amdgcn_rcpf(1.0f + y1);
      acc[d][1] += wv * r1;
    }
  }

  float s0[DT], s1[DT];
#pragma unroll
  for (int d = 0; d < DT; ++d) {
    s0[d] = vsum - acc[d][0];
    s1[d] = vsum - acc[d][1];
  }

  const int lane = tid & 63;
  const int wid = tid >> 6;
  const float L2E = 1.4426950408889634f;
  const float LN2 = 0.6931471805599453f;

  // block max per d
#pragma unroll
  for (int d = 0; d < DT; ++d) {
    float m = fmaxf(s0[d], s1[d]);
#pragma unroll
    for (int o = 32; o >= 1; o >>= 1) m = fmaxf(m, __shfl_xor(m, o, 64));
    if (lane == 0) redm[d][wid] = m;
  }
  __syncthreads();

  float M[DT];
#pragma unroll
  for (int d = 0; d < DT; ++d) {
    float m = redm[d][0];
#pragma unroll
    for (int w = 1; w < 8; ++w) m = fmaxf(m, redm[d][w]);
    M[d] = m;
    float z = __builtin_amdgcn_exp2f((s0[d] - m) * L2E) +
              __builtin_amdgcn_exp2f((s1[d] - m) * L2E);
#pragma unroll
    for (int o = 32; o >= 1; o >>= 1) z += __shfl_xor(z, o, 64);
    if (lane == 0) reds[d][wid] = z;
  }
  __syncthreads();

#pragma unroll
  for (int d = 0; d < DT; ++d) {
    float s = reds[d][0];
#pragma unroll
    for (int w = 1; w < 8; ++w) s += reds[d][w];
    const float lse = M[d] + LN2 * __builtin_amdgcn_logf(s);
    const size_t rowoff = (size_t)(b * DEC_ + d0 + d) * ENC_;
    out[rowoff + tid] = s0[d] - lse;
    out[rowoff + tid + 512] = s1[d] - lse;
  }
}

extern "C" void kernel_launch(void* const* d_in, const int* in_sizes, int n_in,
                              void* d_out, int out_size, void* d_ws, size_t ws_size,
                              hipStream_t stream) {
  const float* xd = (const float*)d_in[0];  // (4,256,256)
  const float* xe = (const float*)d_in[1];  // (4,1024,256)
  const float* w1 = (const float*)d_in[2];  // (256,256)
  const float* w2 = (const float*)d_in[3];  // (256,256)
  const float* v  = (const float*)d_in[4];  // (256,)
  float* out = (float*)d_out;               // (4,256,1024)

  float* encT = (float*)d_ws;                         // 4 MB: [B][H][ENC]
  float* decS = encT + (size_t)B_ * H_ * ENC_;        // 1 MB: [B][DEC][H]

  // K1: 256 enc tiles + 64 dec tiles
  gemm_abt<<<320, 256, 0, stream>>>(w1, xe, xd, w2, encT, decS);
  // K2: one block per (b, 4 d-rows)
  scores_lsm<<<B_ * (DEC_ / DT), 512, 0, stream>>>(encT, decS, v, out);
}

// Round 2
// 98.163 us; speedup vs baseline: 1.0016x; 1.0016x over previous
//
#include <hip/hip_runtime.h>
#include <hip/hip_bf16.h>

// PointerNetwork: scores[b,d,e] = sum_h v[h]*tanh(dec_t[b,d,h] + enc_t[b,e,h]),
// out = log_softmax(scores, axis=e).  B=4, DEC=256, ENC=1024, H=256, fp32.
//
//   K1 (gemm_abt): encT[b][h][e] = SC * (x_enc[b,e,:] . w1[h,:])   (transposed, pre-scaled)
//                  decS[b][d][h] = SC * (x_dec[b,d,:] . w2[h,:])
//                  SC = 2*log2(e)  =>  exp(2x) == exp2(encT+decS).
//   K2 (scores_lsm): block = (b, 2 d-rows) x 1024 threads (one e per thread);
//                  tanh via 1 - 2*rcp(1+exp2(arg)); block log_softmax.

#define B_ 4
#define DEC_ 256
#define ENC_ 1024
#define H_ 256

// ---------------- Kernel 1: fused dual GEMM (A . B^T) * scale ----------------
#define TM 64
#define TN 64
#define TK 32
#define LDP 68   // padded LDS leading dim

__global__ __launch_bounds__(256) void gemm_abt(
    const float* __restrict__ w1, const float* __restrict__ xe,
    const float* __restrict__ xd, const float* __restrict__ w2,
    float* __restrict__ encT, float* __restrict__ decS) {
  const int blk = blockIdx.x;
  const float* A;
  const float* Bm;
  float* C;
  int ldc, tM, tN;
  if (blk < 256) {
    const int b = blk >> 6;
    const int t = blk & 63;       // 4 (tileM over h) x 16 (tileN over e)
    tM = t >> 4; tN = t & 15;
    A = w1;
    Bm = xe + (size_t)b * ENC_ * H_;
    C = encT + (size_t)b * H_ * ENC_;
    ldc = ENC_;
  } else {
    const int blk2 = blk - 256;
    const int b = blk2 >> 4;
    const int t = blk2 & 15;      // 4 x 4
    tM = t >> 2; tN = t & 3;
    A = xd + (size_t)b * DEC_ * H_;
    Bm = w2;
    C = decS + (size_t)b * DEC_ * H_;
    ldc = H_;
  }
  const int K = H_;

  __shared__ __align__(16) float As[TK][LDP];  // k-major: As[k][m]
  __shared__ __align__(16) float Bs[TK][LDP];

  const int tid = threadIdx.x;
  const int tr = tid >> 4;
  const int tc = tid & 15;

  float acc[4][4] = {};

  for (int k0 = 0; k0 < K; k0 += TK) {
    const int lrow = tid >> 3;        // 0..31
    const int lk = (tid & 7) << 2;    // 0,4,...,28
#pragma unroll
    for (int s = 0; s < 2; ++s) {
      const int row = lrow + s * 32;
      float4 a4 = *(const float4*)(A + (size_t)(tM * 64 + row) * K + k0 + lk);
      As[lk + 0][row] = a4.x; As[lk + 1][row] = a4.y;
      As[lk + 2][row] = a4.z; As[lk + 3][row] = a4.w;
      float4 b4 = *(const float4*)(Bm + (size_t)(tN * 64 + row) * K + k0 + lk);
      Bs[lk + 0][row] = b4.x; Bs[lk + 1][row] = b4.y;
      Bs[lk + 2][row] = b4.z; Bs[lk + 3][row] = b4.w;
    }
    __syncthreads();
#pragma unroll
    for (int kk = 0; kk < TK; ++kk) {
      float4 a = *(const float4*)&As[kk][tr << 2];
      float4 b = *(const float4*)&Bs[kk][tc << 2];
      acc[0][0] += a.x * b.x; acc[0][1] += a.x * b.y; acc[0][2] += a.x * b.z; acc[0][3] += a.x * b.w;
      acc[1][0] += a.y * b.x; acc[1][1] += a.y * b.y; acc[1][2] += a.y * b.z; acc[1][3] += a.y * b.w;
      acc[2][0] += a.z * b.x; acc[2][1] += a.z * b.y; acc[2][2] += a.z * b.z; acc[2][3] += a.z * b.w;
      acc[3][0] += a.w * b.x; acc[3][1] += a.w * b.y; acc[3][2] += a.w * b.z; acc[3][3] += a.w * b.w;
    }
    __syncthreads();
  }

  const float SC = 2.8853900817779268f;  // 2*log2(e)
#pragma unroll
  for (int i = 0; i < 4; ++i) {
    const int row = tM * 64 + (tr << 2) + i;
    float4 o;
    o.x = acc[i][0] * SC; o.y = acc[i][1] * SC;
    o.z = acc[i][2] * SC; o.w = acc[i][3] * SC;
    *(float4*)(C + (size_t)row * ldc + (tN << 6) + (tc << 2)) = o;
  }
}

// ---------------- Kernel 2: scores + log_softmax ----------------
// Block = 1024 threads = (b, 2 d-rows). Thread t owns column e = t.
// Grid = 512 blocks -> 2 blocks/CU = 32 waves/CU (occupancy fix vs R0's 8).
// score = Vsum - sum_h (2 v[h]) * rcp(1 + exp2(encT + decS)).

__global__ __launch_bounds__(1024) void scores_lsm(
    const float* __restrict__ encT, const float* __restrict__ decS,
    const float* __restrict__ v, float* __restrict__ out) {
  const int bid = blockIdx.x;
  const int b = bid >> 7;              // 128 d-pairs per batch
  const int d0 = (bid & 127) * 2;
  const int tid = threadIdx.x;         // 0..1023 == e

  __shared__ __align__(16) float4 sdat[H_];   // {dec0, dec1, 2v, -}
  __shared__ float redm[2][16];
  __shared__ float reds[2][16];

  if (tid < H_) {
    const size_t base = (size_t)(b * DEC_ + d0) * H_ + tid;
    sdat[tid] = make_float4(decS[base], decS[base + H_], 2.0f * v[tid], 0.0f);
  }
  __syncthreads();

  const float* ep = encT + (size_t)b * H_ * ENC_ + tid;
  float acc0 = 0.0f, acc1 = 0.0f, vs = 0.0f;

  // prefetch first group
  float eN[4];
#pragma unroll
  for (int i = 0; i < 4; ++i) eN[i] = ep[(size_t)i * ENC_];

  for (int h = 0; h < H_; h += 4) {
    float e[4];
#pragma unroll
    for (int i = 0; i < 4; ++i) e[i] = eN[i];
    if (h + 4 < H_) {
#pragma unroll
      for (int i = 0; i < 4; ++i) eN[i] = ep[(size_t)(h + 4 + i) * ENC_];
    }
#pragma unroll
    for (int i = 0; i < 4; ++i) {
      const float4 sd = sdat[h + i];
      vs += sd.z;
      const float r0 = __builtin_amdgcn_rcpf(1.0f + __builtin_amdgcn_exp2f(e[i] + sd.x));
      acc0 += sd.z * r0;
      const float r1 = __builtin_amdgcn_rcpf(1.0f + __builtin_amdgcn_exp2f(e[i] + sd.y));
      acc1 += sd.z * r1;
    }
  }

  const float vsum = 0.5f * vs;
  float s0 = vsum - acc0;
  float s1 = vsum - acc1;

  const int lane = tid & 63;
  const int wid = tid >> 6;            // 0..15
  const float L2E = 1.4426950408889634f;
  const float LN2 = 0.6931471805599453f;

  // block max per d
  float m0 = s0, m1 = s1;
#pragma unroll
  for (int o = 32; o >= 1; o >>= 1) {
    m0 = fmaxf(m0, __shfl_xor(m0, o, 64));
    m1 = fmaxf(m1, __shfl_xor(m1, o, 64));
  }
  if (lane == 0) { redm[0][wid] = m0; redm[1][wid] = m1; }
  __syncthreads();

  float M0 = redm[0][0], M1 = redm[1][0];
#pragma unroll
  for (int w = 1; w < 16; ++w) {
    M0 = fmaxf(M0, redm[0][w]);
    M1 = fmaxf(M1, redm[1][w]);
  }

  float z0 = __builtin_amdgcn_exp2f((s0 - M0) * L2E);
  float z1 = __builtin_amdgcn_exp2f((s1 - M1) * L2E);
#pragma unroll
  for (int o = 32; o >= 1; o >>= 1) {
    z0 += __shfl_xor(z0, o, 64);
    z1 += __shfl_xor(z1, o, 64);
  }
  if (lane == 0) { reds[0][wid] = z0; reds[1][wid] = z1; }
  __syncthreads();

  float S0 = 0.0f, S1 = 0.0f;
#pragma unroll
  for (int w = 0; w < 16; ++w) { S0 += reds[0][w]; S1 += reds[1][w]; }

  const float lse0 = M0 + LN2 * __builtin_amdgcn_logf(S0);
  const float lse1 = M1 + LN2 * __builtin_amdgcn_logf(S1);

  const size_t rowoff = (size_t)(b * DEC_ + d0) * ENC_;
  out[rowoff + tid] = s0 - lse0;
  out[rowoff + ENC_ + tid] = s1 - lse1;
}

extern "C" void kernel_launch(void* const* d_in, const int* in_sizes, int n_in,
                              void* d_out, int out_size, void* d_ws, size_t ws_size,
                              hipStream_t stream) {
  const float* xd = (const float*)d_in[0];  // (4,256,256)
  const float* xe = (const float*)d_in[1];  // (4,1024,256)
  const float* w1 = (const float*)d_in[2];  // (256,256)
  const float* w2 = (const float*)d_in[3];  // (256,256)
  const float* v  = (const float*)d_in[4];  // (256,)
  float* out = (float*)d_out;               // (4,256,1024)

  float* encT = (float*)d_ws;                         // 4 MB: [B][H][ENC]
  float* decS = encT + (size_t)B_ * H_ * ENC_;        // 1 MB: [B][DEC][H]

  gemm_abt<<<320, 256, 0, stream>>>(w1, xe, xd, w2, encT, decS);
  scores_lsm<<<B_ * (DEC_ / 2), 1024, 0, stream>>>(encT, decS, v, out);
}

// Round 3
// 83.685 us; speedup vs baseline: 1.1749x; 1.1730x over previous
//
#include <hip/hip_runtime.h>
#include <hip/hip_bf16.h>

// PointerNetwork: scores[b,d,e] = sum_h v[h]*tanh(dec_t[b,d,h] + enc_t[b,e,h]),
// out = log_softmax(scores, axis=e).  B=4, DEC=256, ENC=1024, H=256, fp32.
//
// tanh(a+b) = 1 - 2/(1 + e^{2a}e^{2b}).  K1 GEMM epilogue stores
//   encE[b][h][e] = exp2(SC*enc_t),  decE[b][d][h] = exp2(SC*dec_t),  SC=2*log2(e)
// so K2's hot loop is trans-minimal:  r = rcp(fma(Ee, Ed, 1)); acc += 2v*r.
// (R2 post-mortem: exp2+rcp per element = ~32 cy/wave64 of trans issue was the
//  bottleneck; this removes the exp2 -> 268M fewer trans ops.)

#define B_ 4
#define DEC_ 256
#define ENC_ 1024
#define H_ 256

// ---------------- Kernel 1: fused dual GEMM (A . B^T), epilogue exp2 ----------------
#define TM 64
#define TN 64
#define TK 32
#define LDP 68   // padded LDS leading dim

__global__ __launch_bounds__(256) void gemm_abt(
    const float* __restrict__ w1, const float* __restrict__ xe,
    const float* __restrict__ xd, const float* __restrict__ w2,
    float* __restrict__ encE, float* __restrict__ decE) {
  const int blk = blockIdx.x;
  const float* A;
  const float* Bm;
  float* C;
  int ldc, tM, tN;
  if (blk < 256) {
    const int b = blk >> 6;
    const int t = blk & 63;       // 4 (tileM over h) x 16 (tileN over e)
    tM = t >> 4; tN = t & 15;
    A = w1;
    Bm = xe + (size_t)b * ENC_ * H_;
    C = encE + (size_t)b * H_ * ENC_;
    ldc = ENC_;
  } else {
    const int blk2 = blk - 256;
    const int b = blk2 >> 4;
    const int t = blk2 & 15;      // 4 x 4
    tM = t >> 2; tN = t & 3;
    A = xd + (size_t)b * DEC_ * H_;
    Bm = w2;
    C = decE + (size_t)b * DEC_ * H_;
    ldc = H_;
  }
  const int K = H_;

  __shared__ __align__(16) float As[TK][LDP];  // k-major: As[k][m]
  __shared__ __align__(16) float Bs[TK][LDP];

  const int tid = threadIdx.x;
  const int tr = tid >> 4;
  const int tc = tid & 15;

  float acc[4][4] = {};

  for (int k0 = 0; k0 < K; k0 += TK) {
    const int lrow = tid >> 3;        // 0..31
    const int lk = (tid & 7) << 2;    // 0,4,...,28
#pragma unroll
    for (int s = 0; s < 2; ++s) {
      const int row = lrow + s * 32;
      float4 a4 = *(const float4*)(A + (size_t)(tM * 64 + row) * K + k0 + lk);
      As[lk + 0][row] = a4.x; As[lk + 1][row] = a4.y;
      As[lk + 2][row] = a4.z; As[lk + 3][row] = a4.w;
      float4 b4 = *(const float4*)(Bm + (size_t)(tN * 64 + row) * K + k0 + lk);
      Bs[lk + 0][row] = b4.x; Bs[lk + 1][row] = b4.y;
      Bs[lk + 2][row] = b4.z; Bs[lk + 3][row] = b4.w;
    }
    __syncthreads();
#pragma unroll
    for (int kk = 0; kk < TK; ++kk) {
      float4 a = *(const float4*)&As[kk][tr << 2];
      float4 b = *(const float4*)&Bs[kk][tc << 2];
      acc[0][0] += a.x * b.x; acc[0][1] += a.x * b.y; acc[0][2] += a.x * b.z; acc[0][3] += a.x * b.w;
      acc[1][0] += a.y * b.x; acc[1][1] += a.y * b.y; acc[1][2] += a.y * b.z; acc[1][3] += a.y * b.w;
      acc[2][0] += a.z * b.x; acc[2][1] += a.z * b.y; acc[2][2] += a.z * b.z; acc[2][3] += a.z * b.w;
      acc[3][0] += a.w * b.x; acc[3][1] += a.w * b.y; acc[3][2] += a.w * b.z; acc[3][3] += a.w * b.w;
    }
    __syncthreads();
  }

  const float SC = 2.8853900817779268f;  // 2*log2(e)
#pragma unroll
  for (int i = 0; i < 4; ++i) {
    const int row = tM * 64 + (tr << 2) + i;
    float4 o;
    o.x = __builtin_amdgcn_exp2f(acc[i][0] * SC);
    o.y = __builtin_amdgcn_exp2f(acc[i][1] * SC);
    o.z = __builtin_amdgcn_exp2f(acc[i][2] * SC);
    o.w = __builtin_amdgcn_exp2f(acc[i][3] * SC);
    *(float4*)(C + (size_t)row * ldc + (tN << 6) + (tc << 2)) = o;
  }
}

// ---------------- Kernel 2: scores + log_softmax ----------------
// Block = 1024 threads = (b, 2 d-rows). Thread t owns column e = t.
// Grid = 512 -> 2 blocks/CU = 32 waves/CU.
// score = Vsum - sum_h (2 v[h]) * rcp(1 + encE*decE).

__global__ __launch_bounds__(1024) void scores_lsm(
    const float* __restrict__ encE, const float* __restrict__ decE,
    const float* __restrict__ v, float* __restrict__ out) {
  const int bid = blockIdx.x;
  const int b = bid >> 7;              // 128 d-pairs per batch
  const int d0 = (bid & 127) * 2;
  const int tid = threadIdx.x;         // 0..1023 == e

  __shared__ __align__(16) float4 sdat[H_];   // {decE0, decE1, 2v, -}
  __shared__ float redm[2][16];
  __shared__ float reds[2][16];

  if (tid < H_) {
    const size_t base = (size_t)(b * DEC_ + d0) * H_ + tid;
    sdat[tid] = make_float4(decE[base], decE[base + H_], 2.0f * v[tid], 0.0f);
  }
  __syncthreads();

  const float* ep = encE + (size_t)b * H_ * ENC_ + tid;
  float acc0 = 0.0f, acc1 = 0.0f, vs = 0.0f;

  // prefetch first group
  float eN[4];
#pragma unroll
  for (int i = 0; i < 4; ++i) eN[i] = ep[(size_t)i * ENC_];

  for (int h = 0; h < H_; h += 4) {
    float e[4];
#pragma unroll
    for (int i = 0; i < 4; ++i) e[i] = eN[i];
    if (h + 4 < H_) {
#pragma unroll
      for (int i = 0; i < 4; ++i) eN[i] = ep[(size_t)(h + 4 + i) * ENC_];
    }
#pragma unroll
    for (int i = 0; i < 4; ++i) {
      const float4 sd = sdat[h + i];
      vs += sd.z;
      const float r0 = __builtin_amdgcn_rcpf(fmaf(e[i], sd.x, 1.0f));
      acc0 += sd.z * r0;
      const float r1 = __builtin_amdgcn_rcpf(fmaf(e[i], sd.y, 1.0f));
      acc1 += sd.z * r1;
    }
  }

  const float vsum = 0.5f * vs;
  float s0 = vsum - acc0;
  float s1 = vsum - acc1;

  const int lane = tid & 63;
  const int wid = tid >> 6;            // 0..15
  const float L2E = 1.4426950408889634f;
  const float LN2 = 0.6931471805599453f;

  // block max per d
  float m0 = s0, m1 = s1;
#pragma unroll
  for (int o = 32; o >= 1; o >>= 1) {
    m0 = fmaxf(m0, __shfl_xor(m0, o, 64));
    m1 = fmaxf(m1, __shfl_xor(m1, o, 64));
  }
  if (lane == 0) { redm[0][wid] = m0; redm[1][wid] = m1; }
  __syncthreads();

  float M0 = redm[0][0], M1 = redm[1][0];
#pragma unroll
  for (int w = 1; w < 16; ++w) {
    M0 = fmaxf(M0, redm[0][w]);
    M1 = fmaxf(M1, redm[1][w]);
  }

  float z0 = __builtin_amdgcn_exp2f((s0 - M0) * L2E);
  float z1 = __builtin_amdgcn_exp2f((s1 - M1) * L2E);
#pragma unroll
  for (int o = 32; o >= 1; o >>= 1) {
    z0 += __shfl_xor(z0, o, 64);
    z1 += __shfl_xor(z1, o, 64);
  }
  if (lane == 0) { reds[0][wid] = z0; reds[1][wid] = z1; }
  __syncthreads();

  float S0 = 0.0f, S1 = 0.0f;
#pragma unroll
  for (int w = 0; w < 16; ++w) { S0 += reds[0][w]; S1 += reds[1][w]; }

  const float lse0 = M0 + LN2 * __builtin_amdgcn_logf(S0);
  const float lse1 = M1 + LN2 * __builtin_amdgcn_logf(S1);

  const size_t rowoff = (size_t)(b * DEC_ + d0) * ENC_;
  out[rowoff + tid] = s0 - lse0;
  out[rowoff + ENC_ + tid] = s1 - lse1;
}

extern "C" void kernel_launch(void* const* d_in, const int* in_sizes, int n_in,
                              void* d_out, int out_size, void* d_ws, size_t ws_size,
                              hipStream_t stream) {
  const float* xd = (const float*)d_in[0];  // (4,256,256)
  const float* xe = (const float*)d_in[1];  // (4,1024,256)
  const float* w1 = (const float*)d_in[2];  // (256,256)
  const float* w2 = (const float*)d_in[3];  // (256,256)
  const float* v  = (const float*)d_in[4];  // (256,)
  float* out = (float*)d_out;               // (4,256,1024)

  float* encE = (float*)d_ws;                         // 4 MB: [B][H][ENC] = exp2(SC*enc_t)
  float* decE = encE + (size_t)B_ * H_ * ENC_;        // 1 MB: [B][DEC][H] = exp2(SC*dec_t)

  gemm_abt<<<320, 256, 0, stream>>>(w1, xe, xd, w2, encE, decE);
  scores_lsm<<<B_ * (DEC_ / 2), 1024, 0, stream>>>(encE, decE, v, out);
}

// Round 4
// 79.831 us; speedup vs baseline: 1.2316x; 1.0483x over previous
//
#include <hip/hip_runtime.h>
#include <hip/hip_bf16.h>

// PointerNetwork: scores[b,d,e] = sum_h v[h]*tanh(dec_t[b,d,h] + enc_t[b,e,h]),
// out = log_softmax(scores, axis=e).  B=4, DEC=256, ENC=1024, H=256, fp32.
//
// tanh(a+b) = 1 - 2/(1 + e^{2a}e^{2b}).  K1 GEMM epilogue stores
//   encE[b][h][e] = exp2(SC*enc_t),  decE[b][d][h] = exp2(SC*dec_t),  SC=2*log2(e)
// K2 combines FOUR h-terms per reciprocal (R3 post-mortem: v_rcp_f32 issue
// at ~16cy/wave64 was 32 of ~46 busy cy/h):
//   sum_i w_i/m_i = [b*(w0*m1+w1*m0) + a*(w2*m3+w3*m2)] * rcp(a*b),
//   a=m0*m1, b=m2*m3, m_i = fma(e, d_i, 1).   (m<=2^30, 4-prod <2^120: safe)

#define B_ 4
#define DEC_ 256
#define ENC_ 1024
#define H_ 256

// ---------------- Kernel 1: fused dual GEMM (A . B^T), epilogue exp2 ----------------
#define TM 64
#define TN 64
#define TK 32
#define LDP 68   // padded LDS leading dim

__global__ __launch_bounds__(256) void gemm_abt(
    const float* __restrict__ w1, const float* __restrict__ xe,
    const float* __restrict__ xd, const float* __restrict__ w2,
    float* __restrict__ encE, float* __restrict__ decE) {
  const int blk = blockIdx.x;
  const float* A;
  const float* Bm;
  float* C;
  int ldc, tM, tN;
  if (blk < 256) {
    const int b = blk >> 6;
    const int t = blk & 63;       // 4 (tileM over h) x 16 (tileN over e)
    tM = t >> 4; tN = t & 15;
    A = w1;
    Bm = xe + (size_t)b * ENC_ * H_;
    C = encE + (size_t)b * H_ * ENC_;
    ldc = ENC_;
  } else {
    const int blk2 = blk - 256;
    const int b = blk2 >> 4;
    const int t = blk2 & 15;      // 4 x 4
    tM = t >> 2; tN = t & 3;
    A = xd + (size_t)b * DEC_ * H_;
    Bm = w2;
    C = decE + (size_t)b * DEC_ * H_;
    ldc = H_;
  }
  const int K = H_;

  __shared__ __align__(16) float As[TK][LDP];  // k-major: As[k][m]
  __shared__ __align__(16) float Bs[TK][LDP];

  const int tid = threadIdx.x;
  const int tr = tid >> 4;
  const int tc = tid & 15;

  float acc[4][4] = {};

  for (int k0 = 0; k0 < K; k0 += TK) {
    const int lrow = tid >> 3;        // 0..31
    const int lk = (tid & 7) << 2;    // 0,4,...,28
#pragma unroll
    for (int s = 0; s < 2; ++s) {
      const int row = lrow + s * 32;
      float4 a4 = *(const float4*)(A + (size_t)(tM * 64 + row) * K + k0 + lk);
      As[lk + 0][row] = a4.x; As[lk + 1][row] = a4.y;
      As[lk + 2][row] = a4.z; As[lk + 3][row] = a4.w;
      float4 b4 = *(const float4*)(Bm + (size_t)(tN * 64 + row) * K + k0 + lk);
      Bs[lk + 0][row] = b4.x; Bs[lk + 1][row] = b4.y;
      Bs[lk + 2][row] = b4.z; Bs[lk + 3][row] = b4.w;
    }
    __syncthreads();
#pragma unroll
    for (int kk = 0; kk < TK; ++kk) {
      float4 a = *(const float4*)&As[kk][tr << 2];
      float4 b = *(const float4*)&Bs[kk][tc << 2];
      acc[0][0] += a.x * b.x; acc[0][1] += a.x * b.y; acc[0][2] += a.x * b.z; acc[0][3] += a.x * b.w;
      acc[1][0] += a.y * b.x; acc[1][1] += a.y * b.y; acc[1][2] += a.y * b.z; acc[1][3] += a.y * b.w;
      acc[2][0] += a.z * b.x; acc[2][1] += a.z * b.y; acc[2][2] += a.z * b.z; acc[2][3] += a.z * b.w;
      acc[3][0] += a.w * b.x; acc[3][1] += a.w * b.y; acc[3][2] += a.w * b.z; acc[3][3] += a.w * b.w;
    }
    __syncthreads();
  }

  const float SC = 2.8853900817779268f;  // 2*log2(e)
#pragma unroll
  for (int i = 0; i < 4; ++i) {
    const int row = tM * 64 + (tr << 2) + i;
    float4 o;
    o.x = __builtin_amdgcn_exp2f(acc[i][0] * SC);
    o.y = __builtin_amdgcn_exp2f(acc[i][1] * SC);
    o.z = __builtin_amdgcn_exp2f(acc[i][2] * SC);
    o.w = __builtin_amdgcn_exp2f(acc[i][3] * SC);
    *(float4*)(C + (size_t)row * ldc + (tN << 6) + (tc << 2)) = o;
  }
}

// ---------------- Kernel 2: scores + log_softmax ----------------
// Block = 1024 threads = (b, 2 d-rows). Thread t owns column e = t.
// Grid = 512 -> 2 blocks/CU = 32 waves/CU.
// score = Vsum - sum_h (2 v[h]) * rcp(1 + encE*decE), 4 h per rcp.

#define PROC(E0, E1, E2, E3, G)                                        \
  {                                                                    \
    const float4 w4 = sW[G];                                           \
    const float4 da = sA[G];                                           \
    const float4 db = sB[G];                                           \
    vs += (w4.x + w4.y) + (w4.z + w4.w);                               \
    {                                                                  \
      const float m0 = fmaf(E0, da.x, 1.0f);                           \
      const float m1 = fmaf(E1, da.y, 1.0f);                           \
      const float m2 = fmaf(E2, da.z, 1.0f);                           \
      const float m3 = fmaf(E3, da.w, 1.0f);                           \
      const float pa = m0 * m1, pb = m2 * m3;                          \
      const float n01 = fmaf(w4.y, m0, w4.x * m1);                     \
      const float n23 = fmaf(w4.w, m2, w4.z * m3);                     \
      const float num = fmaf(n23, pa, n01 * pb);                       \
      const float r = __builtin_amdgcn_rcpf(pa * pb);                  \
      acc0 = fmaf(num, r, acc0);                                       \
    }                                                                  \
    {                                                                  \
      const float m0 = fmaf(E0, db.x, 1.0f);                           \
      const float m1 = fmaf(E1, db.y, 1.0f);                           \
      const float m2 = fmaf(E2, db.z, 1.0f);                           \
      const float m3 = fmaf(E3, db.w, 1.0f);                           \
      const float pa = m0 * m1, pb = m2 * m3;                          \
      const float n01 = fmaf(w4.y, m0, w4.x * m1);                     \
      const float n23 = fmaf(w4.w, m2, w4.z * m3);                     \
      const float num = fmaf(n23, pa, n01 * pb);                       \
      const float r = __builtin_amdgcn_rcpf(pa * pb);                  \
      acc1 = fmaf(num, r, acc1);                                       \
    }                                                                  \
  }

__global__ __launch_bounds__(1024) void scores_lsm(
    const float* __restrict__ encE, const float* __restrict__ decE,
    const float* __restrict__ v, float* __restrict__ out) {
  const int bid = blockIdx.x;
  const int b = bid >> 7;              // 128 d-pairs per batch
  const int d0 = (bid & 127) * 2;
  const int tid = threadIdx.x;         // 0..1023 == e

  __shared__ __align__(16) float4 sA[H_ / 4];   // decE row d0, packed by 4h
  __shared__ __align__(16) float4 sB[H_ / 4];   // decE row d0+1
  __shared__ __align__(16) float4 sW[H_ / 4];   // 2*v
  __shared__ float redm[2][16];
  __shared__ float reds[2][16];

  if (tid < H_ / 4) {
    const size_t base = (size_t)(b * DEC_ + d0) * H_ + 4 * tid;
    sA[tid] = *(const float4*)(decE + base);
    sB[tid] = *(const float4*)(decE + base + H_);
    float4 w = *(const float4*)(v + 4 * tid);
    sW[tid] = make_float4(2.0f * w.x, 2.0f * w.y, 2.0f * w.z, 2.0f * w.w);
  }
  __syncthreads();

  const float* ep = encE + (size_t)b * H_ * ENC_ + tid;
  float acc0 = 0.0f, acc1 = 0.0f, vs = 0.0f;

  // 2-deep software pipeline over 64 groups of 4 h
  float a0 = ep[0 * ENC_], a1 = ep[1 * ENC_], a2 = ep[2 * ENC_], a3 = ep[3 * ENC_];
  float b0 = ep[4 * ENC_], b1 = ep[5 * ENC_], b2 = ep[6 * ENC_], b3 = ep[7 * ENC_];

  for (int g = 0; g < 64; g += 2) {
    float n0 = 0.f, n1 = 0.f, n2 = 0.f, n3 = 0.f;
    if (g + 2 < 64) {
      const float* p = ep + (size_t)(4 * g + 8) * ENC_;
      n0 = p[0]; n1 = p[ENC_]; n2 = p[2 * ENC_]; n3 = p[3 * ENC_];
    }
    PROC(a0, a1, a2, a3, g)
    a0 = n0; a1 = n1; a2 = n2; a3 = n3;
    if (g + 3 < 64) {
      const float* p = ep + (size_t)(4 * g + 12) * ENC_;
      n0 = p[0]; n1 = p[ENC_]; n2 = p[2 * ENC_]; n3 = p[3 * ENC_];
    }
    PROC(b0, b1, b2, b3, g + 1)
    b0 = n0; b1 = n1; b2 = n2; b3 = n3;
  }

  const float vsum = 0.5f * vs;
  float s0 = vsum - acc0;
  float s1 = vsum - acc1;

  const int lane = tid & 63;
  const int wid = tid >> 6;            // 0..15
  const float L2E = 1.4426950408889634f;
  const float LN2 = 0.6931471805599453f;

  // block max per d
  float m0 = s0, m1 = s1;
#pragma unroll
  for (int o = 32; o >= 1; o >>= 1) {
    m0 = fmaxf(m0, __shfl_xor(m0, o, 64));
    m1 = fmaxf(m1, __shfl_xor(m1, o, 64));
  }
  if (lane == 0) { redm[0][wid] = m0; redm[1][wid] = m1; }
  __syncthreads();

  float M0 = redm[0][0], M1 = redm[1][0];
#pragma unroll
  for (int w = 1; w < 16; ++w) {
    M0 = fmaxf(M0, redm[0][w]);
    M1 = fmaxf(M1, redm[1][w]);
  }

  float z0 = __builtin_amdgcn_exp2f((s0 - M0) * L2E);
  float z1 = __builtin_amdgcn_exp2f((s1 - M1) * L2E);
#pragma unroll
  for (int o = 32; o >= 1; o >>= 1) {
    z0 += __shfl_xor(z0, o, 64);
    z1 += __shfl_xor(z1, o, 64);
  }
  if (lane == 0) { reds[0][wid] = z0; reds[1][wid] = z1; }
  __syncthreads();

  float S0 = 0.0f, S1 = 0.0f;
#pragma unroll
  for (int w = 0; w < 16; ++w) { S0 += reds[0][w]; S1 += reds[1][w]; }

  const float lse0 = M0 + LN2 * __builtin_amdgcn_logf(S0);
  const float lse1 = M1 + LN2 * __builtin_amdgcn_logf(S1);

  const size_t rowoff = (size_t)(b * DEC_ + d0) * ENC_;
  out[rowoff + tid] = s0 - lse0;
  out[rowoff + ENC_ + tid] = s1 - lse1;
}

extern "C" void kernel_launch(void* const* d_in, const int* in_sizes, int n_in,
                              void* d_out, int out_size, void* d_ws, size_t ws_size,
                              hipStream_t stream) {
  const float* xd = (const float*)d_in[0];  // (4,256,256)
  const float* xe = (const float*)d_in[1];  // (4,1024,256)
  const float* w1 = (const float*)d_in[2];  // (256,256)
  const float* w2 = (const float*)d_in[3];  // (256,256)
  const float* v  = (const float*)d_in[4];  // (256,)
  float* out = (float*)d_out;               // (4,256,1024)

  float* encE = (float*)d_ws;                         // 4 MB: [B][H][ENC] = exp2(SC*enc_t)
  float* decE = encE + (size_t)B_ * H_ * ENC_;        // 1 MB: [B][DEC][H] = exp2(SC*dec_t)

  gemm_abt<<<320, 256, 0, stream>>>(w1, xe, xd, w2, encE, decE);
  scores_lsm<<<B_ * (DEC_ / 2), 1024, 0, stream>>>(encE, decE, v, out);
}

// Round 5
// 60.736 us; speedup vs baseline: 1.6188x; 1.3144x over previous
//
#include <hip/hip_runtime.h>
#include <hip/hip_bf16.h>

// PointerNetwork: scores[b,d,e] = sum_h v[h]*tanh(dec_t[b,d,h] + enc_t[b,e,h]),
// out = log_softmax(scores, axis=e).  B=4, DEC=256, ENC=1024, H=256, fp32.
//
// tanh(a+b) = 1 - 2/(1 + e^{2a}e^{2b}).  K1 GEMM epilogue stores
//   encE[b][h][e] = exp2(SC*enc_t),  decE[b][d][h] = exp2(SC*dec_t),  SC=2*log2(e)
// K2: 4 h-terms per reciprocal; decE/v operands read via block-UNIFORM global
// loads -> scalar pipe (s_load_dwordx4), no LDS in the hot loop (R4 post-mortem:
// ds_read_b128 + vs-accum were ~40% of per-group issue).  DT=4 d-rows/block.

#define B_ 4
#define DEC_ 256
#define ENC_ 1024
#define H_ 256

// ---------------- Kernel 1: fused dual GEMM (A . B^T), epilogue exp2 ----------------
#define TM 64
#define TN 64
#define TK 32
#define LDP 68   // padded LDS leading dim

__global__ __launch_bounds__(256) void gemm_abt(
    const float* __restrict__ w1, const float* __restrict__ xe,
    const float* __restrict__ xd, const float* __restrict__ w2,
    float* __restrict__ encE, float* __restrict__ decE) {
  const int blk = blockIdx.x;
  const float* A;
  const float* Bm;
  float* C;
  int ldc, tM, tN;
  if (blk < 256) {
    const int b = blk >> 6;
    const int t = blk & 63;       // 4 (tileM over h) x 16 (tileN over e)
    tM = t >> 4; tN = t & 15;
    A = w1;
    Bm = xe + (size_t)b * ENC_ * H_;
    C = encE + (size_t)b * H_ * ENC_;
    ldc = ENC_;
  } else {
    const int blk2 = blk - 256;
    const int b = blk2 >> 4;
    const int t = blk2 & 15;      // 4 x 4
    tM = t >> 2; tN = t & 3;
    A = xd + (size_t)b * DEC_ * H_;
    Bm = w2;
    C = decE + (size_t)b * DEC_ * H_;
    ldc = H_;
  }
  const int K = H_;

  __shared__ __align__(16) float As[TK][LDP];  // k-major: As[k][m]
  __shared__ __align__(16) float Bs[TK][LDP];

  const int tid = threadIdx.x;
  const int tr = tid >> 4;
  const int tc = tid & 15;

  float acc[4][4] = {};

  for (int k0 = 0; k0 < K; k0 += TK) {
    const int lrow = tid >> 3;        // 0..31
    const int lk = (tid & 7) << 2;    // 0,4,...,28
#pragma unroll
    for (int s = 0; s < 2; ++s) {
      const int row = lrow + s * 32;
      float4 a4 = *(const float4*)(A + (size_t)(tM * 64 + row) * K + k0 + lk);
      As[lk + 0][row] = a4.x; As[lk + 1][row] = a4.y;
      As[lk + 2][row] = a4.z; As[lk + 3][row] = a4.w;
      float4 b4 = *(const float4*)(Bm + (size_t)(tN * 64 + row) * K + k0 + lk);
      Bs[lk + 0][row] = b4.x; Bs[lk + 1][row] = b4.y;
      Bs[lk + 2][row] = b4.z; Bs[lk + 3][row] = b4.w;
    }
    __syncthreads();
#pragma unroll
    for (int kk = 0; kk < TK; ++kk) {
      float4 a = *(const float4*)&As[kk][tr << 2];
      float4 b = *(const float4*)&Bs[kk][tc << 2];
      acc[0][0] += a.x * b.x; acc[0][1] += a.x * b.y; acc[0][2] += a.x * b.z; acc[0][3] += a.x * b.w;
      acc[1][0] += a.y * b.x; acc[1][1] += a.y * b.y; acc[1][2] += a.y * b.z; acc[1][3] += a.y * b.w;
      acc[2][0] += a.z * b.x; acc[2][1] += a.z * b.y; acc[2][2] += a.z * b.z; acc[2][3] += a.z * b.w;
      acc[3][0] += a.w * b.x; acc[3][1] += a.w * b.y; acc[3][2] += a.w * b.z; acc[3][3] += a.w * b.w;
    }
    __syncthreads();
  }

  const float SC = 2.8853900817779268f;  // 2*log2(e)
#pragma unroll
  for (int i = 0; i < 4; ++i) {
    const int row = tM * 64 + (tr << 2) + i;
    float4 o;
    o.x = __builtin_amdgcn_exp2f(acc[i][0] * SC);
    o.y = __builtin_amdgcn_exp2f(acc[i][1] * SC);
    o.z = __builtin_amdgcn_exp2f(acc[i][2] * SC);
    o.w = __builtin_amdgcn_exp2f(acc[i][3] * SC);
    *(float4*)(C + (size_t)row * ldc + (tN << 6) + (tc << 2)) = o;
  }
}

// ---------------- Kernel 2: scores + log_softmax ----------------
// Block = 1024 threads (tid = e), DT=4 d-rows, grid = 256 (1 block/CU).
// score_d = vsum - 2 * sum_groups [n01*pb + n23*pa] * rcp(pa*pb),
//   m_i = fma(E_i, dec_i, 1), pa=m0*m1, pb=m2*m3.
// decE rows + v: block-uniform global reads -> scalar pipe, no LDS.

#define DT 4

// Sum_{i=0..3} w_i/m_i accumulated into ACC (one rcp per 4 terms)
#define PROC1(D4, ACC)                                                 \
  {                                                                    \
    const float m0 = fmaf(E0, (D4).x, 1.0f);                           \
    const float m1 = fmaf(E1, (D4).y, 1.0f);                           \
    const float m2 = fmaf(E2, (D4).z, 1.0f);                           \
    const float m3 = fmaf(E3, (D4).w, 1.0f);                           \
    const float pa = m0 * m1, pb = m2 * m3;                            \
    const float n01 = fmaf(wC.x, m1, wC.y * m0);                       \
    const float n23 = fmaf(wC.z, m3, wC.w * m2);                       \
    const float num = fmaf(n01, pb, n23 * pa);                         \
    ACC = fmaf(num, __builtin_amdgcn_rcpf(pa * pb), ACC);              \
  }

__global__ __launch_bounds__(1024) void scores_lsm(
    const float* __restrict__ encE, const float* __restrict__ decE,
    const float* __restrict__ v, float* __restrict__ out) {
  const int bid = blockIdx.x;          // 256 blocks
  const int b = bid >> 6;              // 64 d-quads per batch
  const int d0 = (bid & 63) * DT;
  const int tid = threadIdx.x;         // 0..1023 == e

  __shared__ float redv[16];
  __shared__ float redm[DT][16];
  __shared__ float reds[DT][16];

  const int lane = tid & 63;
  const int wid = tid >> 6;            // 0..15

  // ---- vsum = sum_h v[h] (prologue block reduce) ----
  float pv = (tid < H_) ? v[tid] : 0.0f;
#pragma unroll
  for (int o = 32; o >= 1; o >>= 1) pv += __shfl_xor(pv, o, 64);
  if (lane == 0) redv[wid] = pv;
  __syncthreads();
  float vsum = 0.0f;
#pragma unroll
  for (int w = 0; w < 4; ++w) vsum += redv[w];   // waves 4..15 hold zeros

  // ---- main loop: 64 groups of 4 h ----
  const float* ep = encE + (size_t)b * H_ * ENC_ + tid;
  const float* dp = decE + (size_t)(b * DEC_ + d0) * H_;   // block-uniform
  float acc0 = 0.0f, acc1 = 0.0f, acc2 = 0.0f, acc3 = 0.0f;

  // current-stage operands
  float E0 = ep[0 * ENC_], E1 = ep[1 * ENC_], E2 = ep[2 * ENC_], E3 = ep[3 * ENC_];
  float4 wC = *(const float4*)(v);                  // uniform -> s_load
  float4 dC0 = *(const float4*)(dp);
  float4 dC1 = *(const float4*)(dp + H_);
  float4 dC2 = *(const float4*)(dp + 2 * H_);
  float4 dC3 = *(const float4*)(dp + 3 * H_);

  for (int g = 0; g < 64; ++g) {
    // prefetch next group's operands
    float N0 = 0.f, N1 = 0.f, N2 = 0.f, N3 = 0.f;
    float4 wN = wC, dN0 = dC0, dN1 = dC1, dN2 = dC2, dN3 = dC3;
    if (g < 63) {
      const float* p = ep + (size_t)(4 * g + 4) * ENC_;
      N0 = p[0]; N1 = p[ENC_]; N2 = p[2 * ENC_]; N3 = p[3 * ENC_];
      const int h4 = 4 * (g + 1);
      wN = *(const float4*)(v + h4);
      dN0 = *(const float4*)(dp + h4);
      dN1 = *(const float4*)(dp + H_ + h4);
      dN2 = *(const float4*)(dp + 2 * H_ + h4);
      dN3 = *(const float4*)(dp + 3 * H_ + h4);
    }
    PROC1(dC0, acc0)
    PROC1(dC1, acc1)
    PROC1(dC2, acc2)
    PROC1(dC3, acc3)
    E0 = N0; E1 = N1; E2 = N2; E3 = N3;
    wC = wN; dC0 = dN0; dC1 = dN1; dC2 = dN2; dC3 = dN3;
  }

  float s[DT];
  s[0] = fmaf(-2.0f, acc0, vsum);
  s[1] = fmaf(-2.0f, acc1, vsum);
  s[2] = fmaf(-2.0f, acc2, vsum);
  s[3] = fmaf(-2.0f, acc3, vsum);

  const float L2E = 1.4426950408889634f;
  const float LN2 = 0.6931471805599453f;

  // ---- block max per d ----
#pragma unroll
  for (int d = 0; d < DT; ++d) {
    float m = s[d];
#pragma unroll
    for (int o = 32; o >= 1; o >>= 1) m = fmaxf(m, __shfl_xor(m, o, 64));
    if (lane == 0) redm[d][wid] = m;
  }
  __syncthreads();

  float M[DT], Z[DT];
#pragma unroll
  for (int d = 0; d < DT; ++d) {
    float m = redm[d][0];
#pragma unroll
    for (int w = 1; w < 16; ++w) m = fmaxf(m, redm[d][w]);
    M[d] = m;
    float z = __builtin_amdgcn_exp2f((s[d] - m) * L2E);
#pragma unroll
    for (int o = 32; o >= 1; o >>= 1) z += __shfl_xor(z, o, 64);
    if (lane == 0) reds[d][wid] = z;
  }
  __syncthreads();

#pragma unroll
  for (int d = 0; d < DT; ++d) {
    float S = 0.0f;
#pragma unroll
    for (int w = 0; w < 16; ++w) S += reds[d][w];
    const float lse = M[d] + LN2 * __builtin_amdgcn_logf(S);
    out[(size_t)(b * DEC_ + d0 + d) * ENC_ + tid] = s[d] - lse;
  }
}

extern "C" void kernel_launch(void* const* d_in, const int* in_sizes, int n_in,
                              void* d_out, int out_size, void* d_ws, size_t ws_size,
                              hipStream_t stream) {
  const float* xd = (const float*)d_in[0];  // (4,256,256)
  const float* xe = (const float*)d_in[1];  // (4,1024,256)
  const float* w1 = (const float*)d_in[2];  // (256,256)
  const float* w2 = (const float*)d_in[3];  // (256,256)
  const float* v  = (const float*)d_in[4];  // (256,)
  float* out = (float*)d_out;               // (4,256,1024)

  float* encE = (float*)d_ws;                         // 4 MB: [B][H][ENC] = exp2(SC*enc_t)
  float* decE = encE + (size_t)B_ * H_ * ENC_;        // 1 MB: [B][DEC][H] = exp2(SC*dec_t)

  gemm_abt<<<320, 256, 0, stream>>>(w1, xe, xd, w2, encE, decE);
  scores_lsm<<<B_ * (DEC_ / DT), 1024, 0, stream>>>(encE, decE, v, out);
}

// Round 6
// 55.539 us; speedup vs baseline: 1.7703x; 1.0936x over previous
//
#include <hip/hip_runtime.h>
#include <hip/hip_bf16.h>

// PointerNetwork: scores[b,d,e] = sum_h v[h]*tanh(dec_t[b,d,h] + enc_t[b,e,h]),
// out = log_softmax(scores, axis=e).  B=4, DEC=256, ENC=1024, H=256, fp32.
//
// tanh(a+b) = 1 - 2/(1 + e^{2a}e^{2b}).
//   K1 (MFMA bf16): encE[b][h][e] = exp2(SC*(x_enc . w1)), decE likewise,
//       SC = 2*log2(e). 64x64 tiles, A.B^T via v_mfma_f32_16x16x32_bf16,
//       inputs rounded fp32->bf16 (err budget ~0.05 << 0.19 threshold).
//   K2: 4 h-terms per rcp, scalar-pipe uniform operands, DT=4 d/block,
//       XCD-pinned batches (R5 post-mortem: 4MB working set == L2 size ->
//       thrash; pinning batch b to XCD pair {2b,2b+1} makes encE L2-hit).

#define B_ 4
#define DEC_ 256
#define ENC_ 1024
#define H_ 256

using bf16x8 = __attribute__((ext_vector_type(8))) short;
using f32x4 = __attribute__((ext_vector_type(4))) float;

__device__ inline short f2bf(float f) {
  union { float f; unsigned u; } x; x.f = f;
  return (short)((x.u + 0x8000u) >> 16);   // round-to-nearest (ties away)
}

__device__ inline bf16x8 cvt8(const float* p) {
  float4 lo = *(const float4*)p;
  float4 hi = *(const float4*)(p + 4);
  bf16x8 r;
  r[0] = f2bf(lo.x); r[1] = f2bf(lo.y); r[2] = f2bf(lo.z); r[3] = f2bf(lo.w);
  r[4] = f2bf(hi.x); r[5] = f2bf(hi.y); r[6] = f2bf(hi.z); r[7] = f2bf(hi.w);
  return r;
}

// ---------------- Kernel 1: dual GEMM (A . B^T) via MFMA, epilogue exp2 ----------------
// blocks 0..255 : enc (A=w1[h][k], Bsrc=xe[b][e][k], C=encE[b][h][e], 4x16 tiles)
// blocks 256..319: dec (A=xd[b][d][k], Bsrc=w2[h][k], C=decE[b][d][h], 4x4 tiles)
// Block = 256 thr = 4 waves in 2x2; wave = 32x32 out (2x2 MFMA subtiles), K=256.

__global__ __launch_bounds__(256) void gemm_mfma(
    const float* __restrict__ w1, const float* __restrict__ xe,
    const float* __restrict__ xd, const float* __restrict__ w2,
    float* __restrict__ encE, float* __restrict__ decE) {
  const int blk = blockIdx.x;
  const float* A;
  const float* Bsrc;
  float* C;
  int ldc, m0, n0;
  if (blk < 256) {
    const int b = blk >> 6;
    const int t = blk & 63;            // 4 (h) x 16 (e)
    m0 = (t >> 4) << 6; n0 = (t & 15) << 6;
    A = w1;
    Bsrc = xe + (size_t)b * ENC_ * H_;
    C = encE + (size_t)b * H_ * ENC_;
    ldc = ENC_;
  } else {
    const int blk2 = blk - 256;
    const int b = blk2 >> 4;
    const int t = blk2 & 15;           // 4 (d) x 4 (h)
    m0 = (t >> 2) << 6; n0 = (t & 3) << 6;
    A = xd + (size_t)b * DEC_ * H_;
    Bsrc = w2;
    C = decE + (size_t)b * DEC_ * H_;
    ldc = H_;
  }
  const int K = H_;
  const int tid = threadIdx.x;
  const int wave = tid >> 6, lane = tid & 63;
  const int wm = (wave >> 1) << 5, wn = (wave & 1) << 5;  // wave: 32x32
  const int fr = lane & 15;            // row within 16
  const int fk = (lane >> 4) << 3;     // k-chunk start (0,8,16,24)

  const float* ap = A + (size_t)(m0 + wm + fr) * K + fk;
  const float* bp = Bsrc + (size_t)(n0 + wn + fr) * K + fk;

  f32x4 acc[2][2] = {};

#pragma unroll
  for (int k0 = 0; k0 < K; k0 += 32) {
    bf16x8 af[2], bf[2];
#pragma unroll
    for (int i = 0; i < 2; ++i) {
      af[i] = cvt8(ap + k0 + (size_t)(i << 4) * K);
      bf[i] = cvt8(bp + k0 + (size_t)(i << 4) * K);
    }
#pragma unroll
    for (int mi = 0; mi < 2; ++mi)
#pragma unroll
      for (int ni = 0; ni < 2; ++ni)
        acc[mi][ni] = __builtin_amdgcn_mfma_f32_16x16x32_bf16(
            af[mi], bf[ni], acc[mi][ni], 0, 0, 0);
  }

  const float SC = 2.8853900817779268f;  // 2*log2(e)
#pragma unroll
  for (int mi = 0; mi < 2; ++mi) {
#pragma unroll
    for (int ni = 0; ni < 2; ++ni) {
      const int row = m0 + wm + (mi << 4) + ((lane >> 4) << 2);
      const int col = n0 + wn + (ni << 4) + (lane & 15);
#pragma unroll
      for (int r = 0; r < 4; ++r)
        C[(size_t)(row + r) * ldc + col] =
            __builtin_amdgcn_exp2f(acc[mi][ni][r] * SC);
    }
  }
}

// ---------------- Kernel 2: scores + log_softmax ----------------
// Block = 1024 threads (tid = e), DT=4 d-rows, grid = 256 (1 block/CU).
// Batch pinned to XCD pair via bid swizzle (dispatch round-robins bid%8->XCD).

#define DT 4

#define PROC1(D4, ACC)                                                 \
  {                                                                    \
    const float m0 = fmaf(E0, (D4).x, 1.0f);                           \
    const float m1 = fmaf(E1, (D4).y, 1.0f);                           \
    const float m2 = fmaf(E2, (D4).z, 1.0f);                           \
    const float m3 = fmaf(E3, (D4).w, 1.0f);                           \
    const float pa = m0 * m1, pb = m2 * m3;                            \
    const float n01 = fmaf(wC.x, m1, wC.y * m0);                       \
    const float n23 = fmaf(wC.z, m3, wC.w * m2);                       \
    const float num = fmaf(n01, pb, n23 * pa);                         \
    ACC = fmaf(num, __builtin_amdgcn_rcpf(pa * pb), ACC);              \
  }

__global__ __launch_bounds__(1024) void scores_lsm(
    const float* __restrict__ encE, const float* __restrict__ decE,
    const float* __restrict__ v, float* __restrict__ out) {
  const int bid = blockIdx.x;          // 256 blocks
  // XCD-pinning swizzle: batch b -> XCDs {2b, 2b+1}
  const int xcd = bid & 7;
  const int b = xcd >> 1;
  const int d0 = ((((bid >> 3) << 1) | (xcd & 1))) * DT;
  const int tid = threadIdx.x;         // 0..1023 == e

  __shared__ float redv[16];
  __shared__ float redm[DT][16];
  __shared__ float reds[DT][16];

  const int lane = tid & 63;
  const int wid = tid >> 6;            // 0..15

  // ---- vsum = sum_h v[h] (prologue block reduce) ----
  float pv = (tid < H_) ? v[tid] : 0.0f;
#pragma unroll
  for (int o = 32; o >= 1; o >>= 1) pv += __shfl_xor(pv, o, 64);
  if (lane == 0) redv[wid] = pv;
  __syncthreads();
  float vsum = 0.0f;
#pragma unroll
  for (int w = 0; w < 4; ++w) vsum += redv[w];   // waves 4..15 hold zeros

  // ---- main loop: 64 groups of 4 h ----
  const float* ep = encE + (size_t)b * H_ * ENC_ + tid;
  const float* dp = decE + (size_t)(b * DEC_ + d0) * H_;   // block-uniform
  float acc0 = 0.0f, acc1 = 0.0f, acc2 = 0.0f, acc3 = 0.0f;

  float E0 = ep[0 * ENC_], E1 = ep[1 * ENC_], E2 = ep[2 * ENC_], E3 = ep[3 * ENC_];
  float4 wC = *(const float4*)(v);
  float4 dC0 = *(const float4*)(dp);
  float4 dC1 = *(const float4*)(dp + H_);
  float4 dC2 = *(const float4*)(dp + 2 * H_);
  float4 dC3 = *(const float4*)(dp + 3 * H_);

  for (int g = 0; g < 64; ++g) {
    float N0 = 0.f, N1 = 0.f, N2 = 0.f, N3 = 0.f;
    float4 wN = wC, dN0 = dC0, dN1 = dC1, dN2 = dC2, dN3 = dC3;
    if (g < 63) {
      const float* p = ep + (size_t)(4 * g + 4) * ENC_;
      N0 = p[0]; N1 = p[ENC_]; N2 = p[2 * ENC_]; N3 = p[3 * ENC_];
      const int h4 = 4 * (g + 1);
      wN = *(const float4*)(v + h4);
      dN0 = *(const float4*)(dp + h4);
      dN1 = *(const float4*)(dp + H_ + h4);
      dN2 = *(const float4*)(dp + 2 * H_ + h4);
      dN3 = *(const float4*)(dp + 3 * H_ + h4);
    }
    PROC1(dC0, acc0)
    PROC1(dC1, acc1)
    PROC1(dC2, acc2)
    PROC1(dC3, acc3)
    E0 = N0; E1 = N1; E2 = N2; E3 = N3;
    wC = wN; dC0 = dN0; dC1 = dN1; dC2 = dN2; dC3 = dN3;
  }

  float s[DT];
  s[0] = fmaf(-2.0f, acc0, vsum);
  s[1] = fmaf(-2.0f, acc1, vsum);
  s[2] = fmaf(-2.0f, acc2, vsum);
  s[3] = fmaf(-2.0f, acc3, vsum);

  const float L2E = 1.4426950408889634f;
  const float LN2 = 0.6931471805599453f;

  // ---- block max per d ----
#pragma unroll
  for (int d = 0; d < DT; ++d) {
    float m = s[d];
#pragma unroll
    for (int o = 32; o >= 1; o >>= 1) m = fmaxf(m, __shfl_xor(m, o, 64));
    if (lane == 0) redm[d][wid] = m;
  }
  __syncthreads();

  float M[DT];
#pragma unroll
  for (int d = 0; d < DT; ++d) {
    float m = redm[d][0];
#pragma unroll
    for (int w = 1; w < 16; ++w) m = fmaxf(m, redm[d][w]);
    M[d] = m;
    float z = __builtin_amdgcn_exp2f((s[d] - m) * L2E);
#pragma unroll
    for (int o = 32; o >= 1; o >>= 1) z += __shfl_xor(z, o, 64);
    if (lane == 0) reds[d][wid] = z;
  }
  __syncthreads();

#pragma unroll
  for (int d = 0; d < DT; ++d) {
    float S = 0.0f;
#pragma unroll
    for (int w = 0; w < 16; ++w) S += reds[d][w];
    const float lse = M[d] + LN2 * __builtin_amdgcn_logf(S);
    out[(size_t)(b * DEC_ + d0 + d) * ENC_ + tid] = s[d] - lse;
  }
}

extern "C" void kernel_launch(void* const* d_in, const int* in_sizes, int n_in,
                              void* d_out, int out_size, void* d_ws, size_t ws_size,
                              hipStream_t stream) {
  const float* xd = (const float*)d_in[0];  // (4,256,256)
  const float* xe = (const float*)d_in[1];  // (4,1024,256)
  const float* w1 = (const float*)d_in[2];  // (256,256)
  const float* w2 = (const float*)d_in[3];  // (256,256)
  const float* v  = (const float*)d_in[4];  // (256,)
  float* out = (float*)d_out;               // (4,256,1024)

  float* encE = (float*)d_ws;                         // 4 MB: [B][H][ENC] = exp2(SC*enc_t)
  float* decE = encE + (size_t)B_ * H_ * ENC_;        // 1 MB: [B][DEC][H] = exp2(SC*dec_t)

  gemm_mfma<<<320, 256, 0, stream>>>(w1, xe, xd, w2, encE, decE);
  scores_lsm<<<B_ * (DEC_ / DT), 1024, 0, stream>>>(encE, decE, v, out);
}

// Round 7
// 48.114 us; speedup vs baseline: 2.0435x; 1.1543x over previous
//
#include <hip/hip_runtime.h>
#include <hip/hip_bf16.h>

// PointerNetwork: scores[b,d,e] = sum_h v[h]*tanh(dec_t[b,d,h] + enc_t[b,e,h]),
// out = log_softmax(scores, axis=e).  B=4, DEC=256, ENC=1024, H=256, fp32.
//
// tanh(a+b) = 1 - 2/(1 + e^{2a}e^{2b}).
//   K1 (MFMA bf16, LDS double-buffered): encE[b][h][e] = exp2(SC*(x_enc.w1)),
//       decE[b][d][h] = exp2(SC*(x_dec.w2)), SC = 2*log2(e).
//       (R6 post-mortem: direct-from-global MFMA was latency-bound at 1.25
//        waves/SIMD; staged coalesced loads + dbuf hide the chain.)
//   K2: 4 h-terms per rcp, scalar-pipe uniform operands, DT=4 d/block,
//       XCD-pinned batches, 2-deep E prefetch (L2 latency > 1-group slack).

#define B_ 4
#define DEC_ 256
#define ENC_ 1024
#define H_ 256

using bf16x8 = __attribute__((ext_vector_type(8))) short;
using f32x4 = __attribute__((ext_vector_type(4))) float;

__device__ inline short f2bf(float f) {
  union { float f; unsigned u; } x; x.f = f;
  return (short)((x.u + 0x8000u) >> 16);   // round-to-nearest
}

// ---------------- Kernel 1: dual GEMM (A . B^T) via MFMA + LDS dbuf ----------------
// blocks 0..255 : enc (A=w1[h][k], Bsrc=xe[b][e][k], C=encE[b][h][e])
// blocks 256..319: dec (A=xd[b][d][k], Bsrc=w2[h][k], C=decE[b][d][h])
// Block = 256 thr = 4 waves (2x2 of 32x32 out); 64x64 tile, K=256 in BK=64 chunks.

#define LDK 72   // padded row stride in shorts: 144B = 16B-aligned, even bank spread

__global__ __launch_bounds__(256) void gemm_mfma(
    const float* __restrict__ w1, const float* __restrict__ xe,
    const float* __restrict__ xd, const float* __restrict__ w2,
    float* __restrict__ encE, float* __restrict__ decE) {
  const int blk = blockIdx.x;
  const float* A;
  const float* Bsrc;
  float* C;
  int ldc, m0, n0;
  if (blk < 256) {
    const int b = blk >> 6;
    const int t = blk & 63;            // 4 (h) x 16 (e)
    m0 = (t >> 4) << 6; n0 = (t & 15) << 6;
    A = w1;
    Bsrc = xe + (size_t)b * ENC_ * H_;
    C = encE + (size_t)b * H_ * ENC_;
    ldc = ENC_;
  } else {
    const int blk2 = blk - 256;
    const int b = blk2 >> 4;
    const int t = blk2 & 15;           // 4 (d) x 4 (h)
    m0 = (t >> 2) << 6; n0 = (t & 3) << 6;
    A = xd + (size_t)b * DEC_ * H_;
    Bsrc = w2;
    C = decE + (size_t)b * DEC_ * H_;
    ldc = H_;
  }
  const int K = H_;
  const int tid = threadIdx.x;
  const int wave = tid >> 6, lane = tid & 63;
  const int wm = (wave >> 1) << 5, wn = (wave & 1) << 5;  // wave: 32x32 out
  const int fr = lane & 15;
  const int fk = (lane >> 4) << 3;     // k-chunk start within 32 (0,8,16,24)

  __shared__ short As[2][64][LDK];
  __shared__ short Bs[2][64][LDK];

  // staging: thread t -> row = t>>2, 16 consecutive k at (t&3)*16
  const int srow = tid >> 2;
  const int skq = (tid & 3) << 4;
  const float* ag = A + (size_t)(m0 + srow) * K + skq;
  const float* bg = Bsrc + (size_t)(n0 + srow) * K + skq;

  float4 ra[4], rb[4];
#define LDCHUNK(K0)                                                    \
  {                                                                    \
    _Pragma("unroll")                                                  \
    for (int i = 0; i < 4; ++i) {                                      \
      ra[i] = *(const float4*)(ag + (K0) + 4 * i);                     \
      rb[i] = *(const float4*)(bg + (K0) + 4 * i);                     \
    }                                                                  \
  }
#define STCHUNK(BUF)                                                   \
  {                                                                    \
    _Pragma("unroll")                                                  \
    for (int j = 0; j < 2; ++j) {                                      \
      bf16x8 pa, pb;                                                   \
      pa[0] = f2bf(ra[2 * j].x);     pa[1] = f2bf(ra[2 * j].y);        \
      pa[2] = f2bf(ra[2 * j].z);     pa[3] = f2bf(ra[2 * j].w);        \
      pa[4] = f2bf(ra[2 * j + 1].x); pa[5] = f2bf(ra[2 * j + 1].y);    \
      pa[6] = f2bf(ra[2 * j + 1].z); pa[7] = f2bf(ra[2 * j + 1].w);    \
      pb[0] = f2bf(rb[2 * j].x);     pb[1] = f2bf(rb[2 * j].y);        \
      pb[2] = f2bf(rb[2 * j].z);     pb[3] = f2bf(rb[2 * j].w);        \
      pb[4] = f2bf(rb[2 * j + 1].x); pb[5] = f2bf(rb[2 * j + 1].y);    \
      pb[6] = f2bf(rb[2 * j + 1].z); pb[7] = f2bf(rb[2 * j + 1].w);    \
      *(bf16x8*)&As[BUF][srow][skq + 8 * j] = pa;                      \
      *(bf16x8*)&Bs[BUF][srow][skq + 8 * j] = pb;                      \
    }                                                                  \
  }

  f32x4 acc[2][2] = {};

#define COMPUTE(BUF)                                                   \
  {                                                                    \
    _Pragma("unroll")                                                  \
    for (int kk = 0; kk < 2; ++kk) {                                   \
      bf16x8 af[2], bff[2];                                            \
      _Pragma("unroll")                                                \
      for (int mi = 0; mi < 2; ++mi)                                   \
        af[mi] = *(const bf16x8*)&As[BUF][wm + (mi << 4) + fr][(kk << 5) + fk]; \
      _Pragma("unroll")                                                \
      for (int ni = 0; ni < 2; ++ni)                                   \
        bff[ni] = *(const bf16x8*)&Bs[BUF][wn + (ni << 4) + fr][(kk << 5) + fk]; \
      _Pragma("unroll")                                                \
      for (int mi = 0; mi < 2; ++mi)                                   \
        _Pragma("unroll")                                              \
        for (int ni = 0; ni < 2; ++ni)                                 \
          acc[mi][ni] = __builtin_amdgcn_mfma_f32_16x16x32_bf16(       \
              af[mi], bff[ni], acc[mi][ni], 0, 0, 0);                  \
    }                                                                  \
  }

  LDCHUNK(0)
  STCHUNK(0)
  __syncthreads();
  // c=0
  LDCHUNK(64) COMPUTE(0) STCHUNK(1) __syncthreads();
  // c=1
  LDCHUNK(128) COMPUTE(1) STCHUNK(0) __syncthreads();
  // c=2
  LDCHUNK(192) COMPUTE(0) STCHUNK(1) __syncthreads();
  // c=3
  COMPUTE(1)

  const float SC = 2.8853900817779268f;  // 2*log2(e)
#pragma unroll
  for (int mi = 0; mi < 2; ++mi) {
#pragma unroll
    for (int ni = 0; ni < 2; ++ni) {
      const int row = m0 + wm + (mi << 4) + ((lane >> 4) << 2);
      const int col = n0 + wn + (ni << 4) + (lane & 15);
#pragma unroll
      for (int r = 0; r < 4; ++r)
        C[(size_t)(row + r) * ldc + col] =
            __builtin_amdgcn_exp2f(acc[mi][ni][r] * SC);
    }
  }
}

// ---------------- Kernel 2: scores + log_softmax ----------------
// Block = 1024 threads (tid = e), DT=4 d-rows, grid = 256 (1 block/CU).
// 2-deep E prefetch; decE/v via block-uniform scalar-pipe loads.

#define DT 4

#define PROC1(D4, ACC)                                                 \
  {                                                                    \
    const float m0 = fmaf(E0, (D4).x, 1.0f);                           \
    const float m1 = fmaf(E1, (D4).y, 1.0f);                           \
    const float m2 = fmaf(E2, (D4).z, 1.0f);                           \
    const float m3 = fmaf(E3, (D4).w, 1.0f);                           \
    const float pa = m0 * m1, pb = m2 * m3;                            \
    const float n01 = fmaf(wC.x, m1, wC.y * m0);                       \
    const float n23 = fmaf(wC.z, m3, wC.w * m2);                       \
    const float num = fmaf(n01, pb, n23 * pa);                         \
    ACC = fmaf(num, __builtin_amdgcn_rcpf(pa * pb), ACC);              \
  }

__global__ __launch_bounds__(1024) void scores_lsm(
    const float* __restrict__ encE, const float* __restrict__ decE,
    const float* __restrict__ v, float* __restrict__ out) {
  const int bid = blockIdx.x;          // 256 blocks
  // XCD-pinning swizzle: batch b -> XCDs {2b, 2b+1}
  const int xcd = bid & 7;
  const int b = xcd >> 1;
  const int d0 = ((((bid >> 3) << 1) | (xcd & 1))) * DT;
  const int tid = threadIdx.x;         // 0..1023 == e

  __shared__ float redv[16];
  __shared__ float redm[DT][16];
  __shared__ float reds[DT][16];

  const int lane = tid & 63;
  const int wid = tid >> 6;            // 0..15

  // ---- vsum = sum_h v[h] ----
  float pv = (tid < H_) ? v[tid] : 0.0f;
#pragma unroll
  for (int o = 32; o >= 1; o >>= 1) pv += __shfl_xor(pv, o, 64);
  if (lane == 0) redv[wid] = pv;
  __syncthreads();
  float vsum = 0.0f;
#pragma unroll
  for (int w = 0; w < 4; ++w) vsum += redv[w];

  // ---- main loop: 64 groups of 4 h, E prefetched 2 groups ahead ----
  const float* ep = encE + (size_t)b * H_ * ENC_ + tid;
  const float* dp = decE + (size_t)(b * DEC_ + d0) * H_;   // block-uniform
  float acc0 = 0.0f, acc1 = 0.0f, acc2 = 0.0f, acc3 = 0.0f;

  float Ec[4], En[4];
#pragma unroll
  for (int i = 0; i < 4; ++i) Ec[i] = ep[(size_t)i * ENC_];
#pragma unroll
  for (int i = 0; i < 4; ++i) En[i] = ep[(size_t)(4 + i) * ENC_];

  float4 wC = *(const float4*)(v);
  float4 dC0 = *(const float4*)(dp);
  float4 dC1 = *(const float4*)(dp + H_);
  float4 dC2 = *(const float4*)(dp + 2 * H_);
  float4 dC3 = *(const float4*)(dp + 3 * H_);

  for (int g = 0; g < 64; ++g) {
    float Et[4] = {0.f, 0.f, 0.f, 0.f};
    if (g + 2 < 64) {
      const float* p = ep + (size_t)(4 * g + 8) * ENC_;
#pragma unroll
      for (int i = 0; i < 4; ++i) Et[i] = p[(size_t)i * ENC_];
    }
    float4 wN = wC, dN0 = dC0, dN1 = dC1, dN2 = dC2, dN3 = dC3;
    if (g < 63) {
      const int h4 = 4 * (g + 1);
      wN = *(const float4*)(v + h4);
      dN0 = *(const float4*)(dp + h4);
      dN1 = *(const float4*)(dp + H_ + h4);
      dN2 = *(const float4*)(dp + 2 * H_ + h4);
      dN3 = *(const float4*)(dp + 3 * H_ + h4);
    }
    const float E0 = Ec[0], E1 = Ec[1], E2 = Ec[2], E3 = Ec[3];
    PROC1(dC0, acc0)
    PROC1(dC1, acc1)
    PROC1(dC2, acc2)
    PROC1(dC3, acc3)
#pragma unroll
    for (int i = 0; i < 4; ++i) { Ec[i] = En[i]; En[i] = Et[i]; }
    wC = wN; dC0 = dN0; dC1 = dN1; dC2 = dN2; dC3 = dN3;
  }

  float s[DT];
  s[0] = fmaf(-2.0f, acc0, vsum);
  s[1] = fmaf(-2.0f, acc1, vsum);
  s[2] = fmaf(-2.0f, acc2, vsum);
  s[3] = fmaf(-2.0f, acc3, vsum);

  const float L2E = 1.4426950408889634f;
  const float LN2 = 0.6931471805599453f;

#pragma unroll
  for (int d = 0; d < DT; ++d) {
    float m = s[d];
#pragma unroll
    for (int o = 32; o >= 1; o >>= 1) m = fmaxf(m, __shfl_xor(m, o, 64));
    if (lane == 0) redm[d][wid] = m;
  }
  __syncthreads();

  float M[DT];
#pragma unroll
  for (int d = 0; d < DT; ++d) {
    float m = redm[d][0];
#pragma unroll
    for (int w = 1; w < 16; ++w) m = fmaxf(m, redm[d][w]);
    M[d] = m;
    float z = __builtin_amdgcn_exp2f((s[d] - m) * L2E);
#pragma unroll
    for (int o = 32; o >= 1; o >>= 1) z += __shfl_xor(z, o, 64);
    if (lane == 0) reds[d][wid] = z;
  }
  __syncthreads();

#pragma unroll
  for (int d = 0; d < DT; ++d) {
    float S = 0.0f;
#pragma unroll
    for (int w = 0; w < 16; ++w) S += reds[d][w];
    const float lse = M[d] + LN2 * __builtin_amdgcn_logf(S);
    out[(size_t)(b * DEC_ + d0 + d) * ENC_ + tid] = s[d] - lse;
  }
}

extern "C" void kernel_launch(void* const* d_in, const int* in_sizes, int n_in,
                              void* d_out, int out_size, void* d_ws, size_t ws_size,
                              hipStream_t stream) {
  const float* xd = (const float*)d_in[0];  // (4,256,256)
  const float* xe = (const float*)d_in[1];  // (4,1024,256)
  const float* w1 = (const float*)d_in[2];  // (256,256)
  const float* w2 = (const float*)d_in[3];  // (256,256)
  const float* v  = (const float*)d_in[4];  // (256,)
  float* out = (float*)d_out;               // (4,256,1024)

  float* encE = (float*)d_ws;                         // 4 MB: [B][H][ENC] = exp2(SC*enc_t)
  float* decE = encE + (size_t)B_ * H_ * ENC_;        // 1 MB: [B][DEC][H] = exp2(SC*dec_t)

  gemm_mfma<<<320, 256, 0, stream>>>(w1, xe, xd, w2, encE, decE);
  scores_lsm<<<B_ * (DEC_ / DT), 1024, 0, stream>>>(encE, decE, v, out);
}

// Round 8
// 45.985 us; speedup vs baseline: 2.1381x; 1.0463x over previous
//
#include <hip/hip_runtime.h>
#include <hip/hip_bf16.h>

// PointerNetwork: scores[b,d,e] = sum_h v[h]*tanh(dec_t[b,d,h] + enc_t[b,e,h]),
// out = log_softmax(scores, axis=e).  B=4, DEC=256, ENC=1024, H=256, fp32.
//
// tanh(a+b) = 1 - 2/(1 + e^{2a}e^{2b}).
//   K1 (MFMA bf16 + LDS dbuf): encE = exp2(SC*(x_enc.w1)), decE = exp2(SC*(x_dec.w2))
//   K2a scores: DT=2 d-rows x 256-e slice per block, grid 2048 -> 8 waves/SIMD
//       (R7 post-mortem: issue work was 19.8us but 50% stall at 4 waves/SIMD;
//        vsum cancels in log_softmax so softmax is split out and occupancy doubled).
//       writes raw -2*acc into d_out.
//   K2b lsm: in-place row log_softmax on d_out.

#define B_ 4
#define DEC_ 256
#define ENC_ 1024
#define H_ 256

using bf16x8 = __attribute__((ext_vector_type(8))) short;
using f32x4 = __attribute__((ext_vector_type(4))) float;

__device__ inline short f2bf(float f) {
  union { float f; unsigned u; } x; x.f = f;
  return (short)((x.u + 0x8000u) >> 16);   // round-to-nearest
}

// ---------------- Kernel 1: dual GEMM (A . B^T) via MFMA + LDS dbuf ----------------
#define LDK 72   // padded row stride in shorts

__global__ __launch_bounds__(256) void gemm_mfma(
    const float* __restrict__ w1, const float* __restrict__ xe,
    const float* __restrict__ xd, const float* __restrict__ w2,
    float* __restrict__ encE, float* __restrict__ decE) {
  const int blk = blockIdx.x;
  const float* A;
  const float* Bsrc;
  float* C;
  int ldc, m0, n0;
  if (blk < 256) {
    const int b = blk >> 6;
    const int t = blk & 63;            // 4 (h) x 16 (e)
    m0 = (t >> 4) << 6; n0 = (t & 15) << 6;
    A = w1;
    Bsrc = xe + (size_t)b * ENC_ * H_;
    C = encE + (size_t)b * H_ * ENC_;
    ldc = ENC_;
  } else {
    const int blk2 = blk - 256;
    const int b = blk2 >> 4;
    const int t = blk2 & 15;           // 4 (d) x 4 (h)
    m0 = (t >> 2) << 6; n0 = (t & 3) << 6;
    A = xd + (size_t)b * DEC_ * H_;
    Bsrc = w2;
    C = decE + (size_t)b * DEC_ * H_;
    ldc = H_;
  }
  const int K = H_;
  const int tid = threadIdx.x;
  const int wave = tid >> 6, lane = tid & 63;
  const int wm = (wave >> 1) << 5, wn = (wave & 1) << 5;
  const int fr = lane & 15;
  const int fk = (lane >> 4) << 3;

  __shared__ short As[2][64][LDK];
  __shared__ short Bs[2][64][LDK];

  const int srow = tid >> 2;
  const int skq = (tid & 3) << 4;
  const float* ag = A + (size_t)(m0 + srow) * K + skq;
  const float* bg = Bsrc + (size_t)(n0 + srow) * K + skq;

  float4 ra[4], rb[4];
#define LDCHUNK(K0)                                                    \
  {                                                                    \
    _Pragma("unroll")                                                  \
    for (int i = 0; i < 4; ++i) {                                      \
      ra[i] = *(const float4*)(ag + (K0) + 4 * i);                     \
      rb[i] = *(const float4*)(bg + (K0) + 4 * i);                     \
    }                                                                  \
  }
#define STCHUNK(BUF)                                                   \
  {                                                                    \
    _Pragma("unroll")                                                  \
    for (int j = 0; j < 2; ++j) {                                      \
      bf16x8 pa, pb;                                                   \
      pa[0] = f2bf(ra[2 * j].x);     pa[1] = f2bf(ra[2 * j].y);        \
      pa[2] = f2bf(ra[2 * j].z);     pa[3] = f2bf(ra[2 * j].w);        \
      pa[4] = f2bf(ra[2 * j + 1].x); pa[5] = f2bf(ra[2 * j + 1].y);    \
      pa[6] = f2bf(ra[2 * j + 1].z); pa[7] = f2bf(ra[2 * j + 1].w);    \
      pb[0] = f2bf(rb[2 * j].x);     pb[1] = f2bf(rb[2 * j].y);        \
      pb[2] = f2bf(rb[2 * j].z);     pb[3] = f2bf(rb[2 * j].w);        \
      pb[4] = f2bf(rb[2 * j + 1].x); pb[5] = f2bf(rb[2 * j + 1].y);    \
      pb[6] = f2bf(rb[2 * j + 1].z); pb[7] = f2bf(rb[2 * j + 1].w);    \
      *(bf16x8*)&As[BUF][srow][skq + 8 * j] = pa;                      \
      *(bf16x8*)&Bs[BUF][srow][skq + 8 * j] = pb;                      \
    }                                                                  \
  }

  f32x4 acc[2][2] = {};

#define COMPUTE(BUF)                                                   \
  {                                                                    \
    _Pragma("unroll")                                                  \
    for (int kk = 0; kk < 2; ++kk) {                                   \
      bf16x8 af[2], bff[2];                                            \
      _Pragma("unroll")                                                \
      for (int mi = 0; mi < 2; ++mi)                                   \
        af[mi] = *(const bf16x8*)&As[BUF][wm + (mi << 4) + fr][(kk << 5) + fk]; \
      _Pragma("unroll")                                                \
      for (int ni = 0; ni < 2; ++ni)                                   \
        bff[ni] = *(const bf16x8*)&Bs[BUF][wn + (ni << 4) + fr][(kk << 5) + fk]; \
      _Pragma("unroll")                                                \
      for (int mi = 0; mi < 2; ++mi)                                   \
        _Pragma("unroll")                                              \
        for (int ni = 0; ni < 2; ++ni)                                 \
          acc[mi][ni] = __builtin_amdgcn_mfma_f32_16x16x32_bf16(       \
              af[mi], bff[ni], acc[mi][ni], 0, 0, 0);                  \
    }                                                                  \
  }

  LDCHUNK(0)
  STCHUNK(0)
  __syncthreads();
  LDCHUNK(64) COMPUTE(0) STCHUNK(1) __syncthreads();
  LDCHUNK(128) COMPUTE(1) STCHUNK(0) __syncthreads();
  LDCHUNK(192) COMPUTE(0) STCHUNK(1) __syncthreads();
  COMPUTE(1)

  const float SC = 2.8853900817779268f;  // 2*log2(e)
#pragma unroll
  for (int mi = 0; mi < 2; ++mi) {
#pragma unroll
    for (int ni = 0; ni < 2; ++ni) {
      const int row = m0 + wm + (mi << 4) + ((lane >> 4) << 2);
      const int col = n0 + wn + (ni << 4) + (lane & 15);
#pragma unroll
      for (int r = 0; r < 4; ++r)
        C[(size_t)(row + r) * ldc + col] =
            __builtin_amdgcn_exp2f(acc[mi][ni][r] * SC);
    }
  }
}

// ---------------- Kernel 2a: raw scores ----------------
// Block = 256 thr = one 256-e slice; DT=2 d-rows; grid = 2048 -> 8 waves/SIMD.
// Writes out[b,d,e] = -2 * sum_groups [...] (vsum cancels in log_softmax).
// decE/v operands are block-uniform -> scalar pipe.

#define PROC1(D4, ACC)                                                 \
  {                                                                    \
    const float m0 = fmaf(E0, (D4).x, 1.0f);                           \
    const float m1 = fmaf(E1, (D4).y, 1.0f);                           \
    const float m2 = fmaf(E2, (D4).z, 1.0f);                           \
    const float m3 = fmaf(E3, (D4).w, 1.0f);                           \
    const float pa = m0 * m1, pb = m2 * m3;                            \
    const float n01 = fmaf(wC.x, m1, wC.y * m0);                       \
    const float n23 = fmaf(wC.z, m3, wC.w * m2);                       \
    const float num = fmaf(n01, pb, n23 * pa);                         \
    ACC = fmaf(num, __builtin_amdgcn_rcpf(pa * pb), ACC);              \
  }

__global__ __launch_bounds__(256) void scores_k(
    const float* __restrict__ encE, const float* __restrict__ decE,
    const float* __restrict__ v, float* __restrict__ out) {
  const int bid = blockIdx.x;            // 0..2047
  // XCD pinning: batch b -> XCDs {2b, 2b+1}
  const int xcd = bid & 7;
  const int b = xcd >> 1;
  const int sub = ((bid >> 3) << 1) | (xcd & 1);   // 0..511 within batch
  const int es = sub & 3;                // e-slice
  const int d0 = (sub >> 2) << 1;        // 0,2,...,254
  const int e = (es << 8) + threadIdx.x;

  const float* ep = encE + (size_t)b * H_ * ENC_ + e;
  const float* dp = decE + (size_t)(b * DEC_ + d0) * H_;   // block-uniform
  float acc0 = 0.0f, acc1 = 0.0f;

#pragma unroll 4
  for (int g = 0; g < 64; ++g) {
    const int h = g << 2;
    const float E0 = ep[(size_t)h * ENC_];
    const float E1 = ep[(size_t)(h + 1) * ENC_];
    const float E2 = ep[(size_t)(h + 2) * ENC_];
    const float E3 = ep[(size_t)(h + 3) * ENC_];
    const float4 wC = *(const float4*)(v + h);
    const float4 dA = *(const float4*)(dp + h);
    const float4 dB = *(const float4*)(dp + H_ + h);
    PROC1(dA, acc0)
    PROC1(dB, acc1)
  }

  float* orow = out + (size_t)(b * DEC_ + d0) * ENC_ + e;
  orow[0] = -2.0f * acc0;
  orow[ENC_] = -2.0f * acc1;
}

// ---------------- Kernel 2b: in-place row log_softmax ----------------
// 1 row (1024 f32) per block, 256 thr x float4.

__global__ __launch_bounds__(256) void lsm_k(float* __restrict__ out) {
  const int row = blockIdx.x;            // 0..1023
  float* p = out + (size_t)row * ENC_;
  const int tid = threadIdx.x;
  const int lane = tid & 63, wid = tid >> 6;

  __shared__ float rm[4], rs[4];

  float4 x = *(const float4*)(p + 4 * tid);

  float m = fmaxf(fmaxf(x.x, x.y), fmaxf(x.z, x.w));
#pragma unroll
  for (int o = 32; o >= 1; o >>= 1) m = fmaxf(m, __shfl_xor(m, o, 64));
  if (lane == 0) rm[wid] = m;
  __syncthreads();
  const float M = fmaxf(fmaxf(rm[0], rm[1]), fmaxf(rm[2], rm[3]));

  const float L2E = 1.4426950408889634f;
  const float LN2 = 0.6931471805599453f;
  float z = __builtin_amdgcn_exp2f((x.x - M) * L2E) +
            __builtin_amdgcn_exp2f((x.y - M) * L2E) +
            __builtin_amdgcn_exp2f((x.z - M) * L2E) +
            __builtin_amdgcn_exp2f((x.w - M) * L2E);
#pragma unroll
  for (int o = 32; o >= 1; o >>= 1) z += __shfl_xor(z, o, 64);
  if (lane == 0) rs[wid] = z;
  __syncthreads();
  const float S = (rs[0] + rs[1]) + (rs[2] + rs[3]);

  const float lse = M + LN2 * __builtin_amdgcn_logf(S);
  x.x -= lse; x.y -= lse; x.z -= lse; x.w -= lse;
  *(float4*)(p + 4 * tid) = x;
}

extern "C" void kernel_launch(void* const* d_in, const int* in_sizes, int n_in,
                              void* d_out, int out_size, void* d_ws, size_t ws_size,
                              hipStream_t stream) {
  const float* xd = (const float*)d_in[0];  // (4,256,256)
  const float* xe = (const float*)d_in[1];  // (4,1024,256)
  const float* w1 = (const float*)d_in[2];  // (256,256)
  const float* w2 = (const float*)d_in[3];  // (256,256)
  const float* v  = (const float*)d_in[4];  // (256,)
  float* out = (float*)d_out;               // (4,256,1024)

  float* encE = (float*)d_ws;                         // 4 MB: [B][H][ENC] = exp2(SC*enc_t)
  float* decE = encE + (size_t)B_ * H_ * ENC_;        // 1 MB: [B][DEC][H] = exp2(SC*dec_t)

  gemm_mfma<<<320, 256, 0, stream>>>(w1, xe, xd, w2, encE, decE);
  scores_k<<<2048, 256, 0, stream>>>(encE, decE, v, out);
  lsm_k<<<B_ * DEC_, 256, 0, stream>>>(out);
}

// Round 9
// 45.393 us; speedup vs baseline: 2.1660x; 1.0130x over previous
//
#include <hip/hip_runtime.h>
#include <hip/hip_bf16.h>

// PointerNetwork: scores[b,d,e] = sum_h v[h]*tanh(dec_t[b,d,h] + enc_t[b,e,h]),
// out = log_softmax(scores, axis=e).  B=4, DEC=256, ENC=1024, H=256, fp32.
//
// tanh(a+b) = 1 - 2/(1 + e^{2a}e^{2b}).
//   K1 (MFMA bf16 + LDS dbuf): encE = exp2(SC*(x_enc.w1)), decE = exp2(SC*(x_dec.w2))
//   K2a scores: block = 8 waves sharing one 64-e slice, each wave its own
//       d-pair (R8 post-mortem: per-block encE re-read was 512MB of L2
//       traffic; sharing E across waves cuts it 8x while keeping 8 waves/SIMD).
//       Writes raw -2*acc (vsum cancels in log_softmax).
//   K2b lsm: in-place row log_softmax on d_out.

#define B_ 4
#define DEC_ 256
#define ENC_ 1024
#define H_ 256

using bf16x8 = __attribute__((ext_vector_type(8))) short;
using f32x4 = __attribute__((ext_vector_type(4))) float;

__device__ inline short f2bf(float f) {
  union { float f; unsigned u; } x; x.f = f;
  return (short)((x.u + 0x8000u) >> 16);   // round-to-nearest
}

// ---------------- Kernel 1: dual GEMM (A . B^T) via MFMA + LDS dbuf ----------------
#define LDK 72   // padded row stride in shorts

__global__ __launch_bounds__(256) void gemm_mfma(
    const float* __restrict__ w1, const float* __restrict__ xe,
    const float* __restrict__ xd, const float* __restrict__ w2,
    float* __restrict__ encE, float* __restrict__ decE) {
  const int blk = blockIdx.x;
  const float* A;
  const float* Bsrc;
  float* C;
  int ldc, m0, n0;
  if (blk < 256) {
    const int b = blk >> 6;
    const int t = blk & 63;            // 4 (h) x 16 (e)
    m0 = (t >> 4) << 6; n0 = (t & 15) << 6;
    A = w1;
    Bsrc = xe + (size_t)b * ENC_ * H_;
    C = encE + (size_t)b * H_ * ENC_;
    ldc = ENC_;
  } else {
    const int blk2 = blk - 256;
    const int b = blk2 >> 4;
    const int t = blk2 & 15;           // 4 (d) x 4 (h)
    m0 = (t >> 2) << 6; n0 = (t & 3) << 6;
    A = xd + (size_t)b * DEC_ * H_;
    Bsrc = w2;
    C = decE + (size_t)b * DEC_ * H_;
    ldc = H_;
  }
  const int K = H_;
  const int tid = threadIdx.x;
  const int wave = tid >> 6, lane = tid & 63;
  const int wm = (wave >> 1) << 5, wn = (wave & 1) << 5;
  const int fr = lane & 15;
  const int fk = (lane >> 4) << 3;

  __shared__ short As[2][64][LDK];
  __shared__ short Bs[2][64][LDK];

  const int srow = tid >> 2;
  const int skq = (tid & 3) << 4;
  const float* ag = A + (size_t)(m0 + srow) * K + skq;
  const float* bg = Bsrc + (size_t)(n0 + srow) * K + skq;

  float4 ra[4], rb[4];
#define LDCHUNK(K0)                                                    \
  {                                                                    \
    _Pragma("unroll")                                                  \
    for (int i = 0; i < 4; ++i) {                                      \
      ra[i] = *(const float4*)(ag + (K0) + 4 * i);                     \
      rb[i] = *(const float4*)(bg + (K0) + 4 * i);                     \
    }                                                                  \
  }
#define STCHUNK(BUF)                                                   \
  {                                                                    \
    _Pragma("unroll")                                                  \
    for (int j = 0; j < 2; ++j) {                                      \
      bf16x8 pa, pb;                                                   \
      pa[0] = f2bf(ra[2 * j].x);     pa[1] = f2bf(ra[2 * j].y);        \
      pa[2] = f2bf(ra[2 * j].z);     pa[3] = f2bf(ra[2 * j].w);        \
      pa[4] = f2bf(ra[2 * j + 1].x); pa[5] = f2bf(ra[2 * j + 1].y);    \
      pa[6] = f2bf(ra[2 * j + 1].z); pa[7] = f2bf(ra[2 * j + 1].w);    \
      pb[0] = f2bf(rb[2 * j].x);     pb[1] = f2bf(rb[2 * j].y);        \
      pb[2] = f2bf(rb[2 * j].z);     pb[3] = f2bf(rb[2 * j].w);        \
      pb[4] = f2bf(rb[2 * j + 1].x); pb[5] = f2bf(rb[2 * j + 1].y);    \
      pb[6] = f2bf(rb[2 * j + 1].z); pb[7] = f2bf(rb[2 * j + 1].w);    \
      *(bf16x8*)&As[BUF][srow][skq + 8 * j] = pa;                      \
      *(bf16x8*)&Bs[BUF][srow][skq + 8 * j] = pb;                      \
    }                                                                  \
  }

  f32x4 acc[2][2] = {};

#define COMPUTE(BUF)                                                   \
  {                                                                    \
    _Pragma("unroll")                                                  \
    for (int kk = 0; kk < 2; ++kk) {                                   \
      bf16x8 af[2], bff[2];                                            \
      _Pragma("unroll")                                                \
      for (int mi = 0; mi < 2; ++mi)                                   \
        af[mi] = *(const bf16x8*)&As[BUF][wm + (mi << 4) + fr][(kk << 5) + fk]; \
      _Pragma("unroll")                                                \
      for (int ni = 0; ni < 2; ++ni)                                   \
        bff[ni] = *(const bf16x8*)&Bs[BUF][wn + (ni << 4) + fr][(kk << 5) + fk]; \
      _Pragma("unroll")                                                \
      for (int mi = 0; mi < 2; ++mi)                                   \
        _Pragma("unroll")                                              \
        for (int ni = 0; ni < 2; ++ni)                                 \
          acc[mi][ni] = __builtin_amdgcn_mfma_f32_16x16x32_bf16(       \
              af[mi], bff[ni], acc[mi][ni], 0, 0, 0);                  \
    }                                                                  \
  }

  LDCHUNK(0)
  STCHUNK(0)
  __syncthreads();
  LDCHUNK(64) COMPUTE(0) STCHUNK(1) __syncthreads();
  LDCHUNK(128) COMPUTE(1) STCHUNK(0) __syncthreads();
  LDCHUNK(192) COMPUTE(0) STCHUNK(1) __syncthreads();
  COMPUTE(1)

  const float SC = 2.8853900817779268f;  // 2*log2(e)
#pragma unroll
  for (int mi = 0; mi < 2; ++mi) {
#pragma unroll
    for (int ni = 0; ni < 2; ++ni) {
      const int row = m0 + wm + (mi << 4) + ((lane >> 4) << 2);
      const int col = n0 + wn + (ni << 4) + (lane & 15);
#pragma unroll
      for (int r = 0; r < 4; ++r)
        C[(size_t)(row + r) * ldc + col] =
            __builtin_amdgcn_exp2f(acc[mi][ni][r] * SC);
    }
  }
}

// ---------------- Kernel 2a: raw scores ----------------
// Block = 512 thr = 8 waves. ALL waves share one 64-e slice (lane -> e);
// wave w owns d-pair (d0+2w, d0+2w+1). Grid = 1024 -> 4 blocks/CU = 8 waves/SIMD.
// encE slice lines are read by all 8 waves -> L1 hits; L2 traffic 64 MB total.

#define PROC1(D4, ACC)                                                 \
  {                                                                    \
    const float m0 = fmaf(E0, (D4).x, 1.0f);                           \
    const float m1 = fmaf(E1, (D4).y, 1.0f);                           \
    const float m2 = fmaf(E2, (D4).z, 1.0f);                           \
    const float m3 = fmaf(E3, (D4).w, 1.0f);                           \
    const float pa = m0 * m1, pb = m2 * m3;                            \
    const float n01 = fmaf(wC.x, m1, wC.y * m0);                       \
    const float n23 = fmaf(wC.z, m3, wC.w * m2);                       \
    const float num = fmaf(n01, pb, n23 * pa);                         \
    ACC = fmaf(num, __builtin_amdgcn_rcpf(pa * pb), ACC);              \
  }

__global__ __launch_bounds__(512) void scores_k(
    const float* __restrict__ encE, const float* __restrict__ decE,
    const float* __restrict__ v, float* __restrict__ out) {
  const int bid = blockIdx.x;            // 0..1023
  // XCD pinning: batch b -> XCDs {2b, 2b+1}
  const int xcd = bid & 7;
  const int b = xcd >> 1;
  const int rem = ((bid >> 3) << 1) | (xcd & 1);   // 0..255 within batch
  const int es = rem & 15;               // e-slice (64 e)
  const int d0 = (rem >> 4) << 4;        // d-group of 16
  const int tid = threadIdx.x;
  const int lane = tid & 63;
  const int wid = __builtin_amdgcn_readfirstlane(tid >> 6);  // 0..7, SGPR

  const int e = (es << 6) + lane;
  const int d = d0 + (wid << 1);

  const float* ep = encE + (size_t)b * H_ * ENC_ + e;
  const float* dp = decE + (size_t)(b * DEC_ + d) * H_;   // wave-uniform (SGPR)
  float acc0 = 0.0f, acc1 = 0.0f;

#pragma unroll 8
  for (int g = 0; g < 64; ++g) {
    const int h = g << 2;
    const float E0 = ep[(size_t)h * ENC_];
    const float E1 = ep[(size_t)(h + 1) * ENC_];
    const float E2 = ep[(size_t)(h + 2) * ENC_];
    const float E3 = ep[(size_t)(h + 3) * ENC_];
    const float4 wC = *(const float4*)(v + h);
    const float4 dA = *(const float4*)(dp + h);
    const float4 dB = *(const float4*)(dp + H_ + h);
    PROC1(dA, acc0)
    PROC1(dB, acc1)
  }

  float* orow = out + (size_t)(b * DEC_ + d) * ENC_ + e;
  orow[0] = -2.0f * acc0;
  orow[ENC_] = -2.0f * acc1;
}

// ---------------- Kernel 2b: in-place row log_softmax ----------------
// 1 row (1024 f32) per block, 256 thr x float4.

__global__ __launch_bounds__(256) void lsm_k(float* __restrict__ out) {
  const int row = blockIdx.x;            // 0..1023
  float* p = out + (size_t)row * ENC_;
  const int tid = threadIdx.x;
  const int lane = tid & 63, wid = tid >> 6;

  __shared__ float rm[4], rs[4];

  float4 x = *(const float4*)(p + 4 * tid);

  float m = fmaxf(fmaxf(x.x, x.y), fmaxf(x.z, x.w));
#pragma unroll
  for (int o = 32; o >= 1; o >>= 1) m = fmaxf(m, __shfl_xor(m, o, 64));
  if (lane == 0) rm[wid] = m;
  __syncthreads();
  const float M = fmaxf(fmaxf(rm[0], rm[1]), fmaxf(rm[2], rm[3]));

  const float L2E = 1.4426950408889634f;
  const float LN2 = 0.6931471805599453f;
  float z = __builtin_amdgcn_exp2f((x.x - M) * L2E) +
            __builtin_amdgcn_exp2f((x.y - M) * L2E) +
            __builtin_amdgcn_exp2f((x.z - M) * L2E) +
            __builtin_amdgcn_exp2f((x.w - M) * L2E);
#pragma unroll
  for (int o = 32; o >= 1; o >>= 1) z += __shfl_xor(z, o, 64);
  if (lane == 0) rs[wid] = z;
  __syncthreads();
  const float S = (rs[0] + rs[1]) + (rs[2] + rs[3]);

  const float lse = M + LN2 * __builtin_amdgcn_logf(S);
  x.x -= lse; x.y -= lse; x.z -= lse; x.w -= lse;
  *(float4*)(p + 4 * tid) = x;
}

extern "C" void kernel_launch(void* const* d_in, const int* in_sizes, int n_in,
                              void* d_out, int out_size, void* d_ws, size_t ws_size,
                              hipStream_t stream) {
  const float* xd = (const float*)d_in[0];  // (4,256,256)
  const float* xe = (const float*)d_in[1];  // (4,1024,256)
  const float* w1 = (const float*)d_in[2];  // (256,256)
  const float* w2 = (const float*)d_in[3];  // (256,256)
  const float* v  = (const float*)d_in[4];  // (256,)
  float* out = (float*)d_out;               // (4,256,1024)

  float* encE = (float*)d_ws;                         // 4 MB: [B][H][ENC] = exp2(SC*enc_t)
  float* decE = encE + (size_t)B_ * H_ * ENC_;        // 1 MB: [B][DEC][H] = exp2(SC*dec_t)

  gemm_mfma<<<320, 256, 0, stream>>>(w1, xe, xd, w2, encE, decE);
  scores_k<<<1024, 512, 0, stream>>>(encE, decE, v, out);
  lsm_k<<<B_ * DEC_, 256, 0, stream>>>(out);
}

// Round 10
// 44.115 us; speedup vs baseline: 2.2287x; 1.0290x over previous
//
#include <hip/hip_runtime.h>
#include <hip/hip_bf16.h>

// PointerNetwork: scores[b,d,e] = sum_h v[h]*tanh(dec_t[b,d,h] + enc_t[b,e,h]),
// out = log_softmax(scores, axis=e).  B=4, DEC=256, ENC=1024, H=256, fp32.
//
// tanh(a+b) = 1 - 2/(1 + e^{2a}e^{2b}).
//   K1 (MFMA bf16 + LDS dbuf): encE = exp2(SC*(x_enc.w1)), decE = exp2(SC*(x_dec.w2))
//   K2a scores: R9 post-mortem — occupancy & L2-reuse fixes were both flat;
//       the stall is per-wave strided global-load latency. This round the E
//       slice lives in LDS: [64e][256h] f32, transposed + XOR-swizzled
//       (chunk ^= row&7), ONE ds_read_b128 per 4h-group. Block = 64e x 32d,
//       1024 thr, 64KB LDS, 2 blocks/CU -> 8 waves/SIMD.
//   K2b lsm: in-place row log_softmax on d_out.

#define B_ 4
#define DEC_ 256
#define ENC_ 1024
#define H_ 256

using bf16x8 = __attribute__((ext_vector_type(8))) short;
using f32x4 = __attribute__((ext_vector_type(4))) float;

__device__ inline short f2bf(float f) {
  union { float f; unsigned u; } x; x.f = f;
  return (short)((x.u + 0x8000u) >> 16);   // round-to-nearest
}

// ---------------- Kernel 1: dual GEMM (A . B^T) via MFMA + LDS dbuf ----------------
#define LDK 72   // padded row stride in shorts

__global__ __launch_bounds__(256) void gemm_mfma(
    const float* __restrict__ w1, const float* __restrict__ xe,
    const float* __restrict__ xd, const float* __restrict__ w2,
    float* __restrict__ encE, float* __restrict__ decE) {
  const int blk = blockIdx.x;
  const float* A;
  const float* Bsrc;
  float* C;
  int ldc, m0, n0;
  if (blk < 256) {
    const int b = blk >> 6;
    const int t = blk & 63;            // 4 (h) x 16 (e)
    m0 = (t >> 4) << 6; n0 = (t & 15) << 6;
    A = w1;
    Bsrc = xe + (size_t)b * ENC_ * H_;
    C = encE + (size_t)b * H_ * ENC_;
    ldc = ENC_;
  } else {
    const int blk2 = blk - 256;
    const int b = blk2 >> 4;
    const int t = blk2 & 15;           // 4 (d) x 4 (h)
    m0 = (t >> 2) << 6; n0 = (t & 3) << 6;
    A = xd + (size_t)b * DEC_ * H_;
    Bsrc = w2;
    C = decE + (size_t)b * DEC_ * H_;
    ldc = H_;
  }
  const int K = H_;
  const int tid = threadIdx.x;
  const int wave = tid >> 6, lane = tid & 63;
  const int wm = (wave >> 1) << 5, wn = (wave & 1) << 5;
  const int fr = lane & 15;
  const int fk = (lane >> 4) << 3;

  __shared__ short As[2][64][LDK];
  __shared__ short Bs[2][64][LDK];

  const int srow = tid >> 2;
  const int skq = (tid & 3) << 4;
  const float* ag = A + (size_t)(m0 + srow) * K + skq;
  const float* bg = Bsrc + (size_t)(n0 + srow) * K + skq;

  float4 ra[4], rb[4];
#define LDCHUNK(K0)                                                    \
  {                                                                    \
    _Pragma("unroll")                                                  \
    for (int i = 0; i < 4; ++i) {                                      \
      ra[i] = *(const float4*)(ag + (K0) + 4 * i);                     \
      rb[i] = *(const float4*)(bg + (K0) + 4 * i);                     \
    }                                                                  \
  }
#define STCHUNK(BUF)                                                   \
  {                                                                    \
    _Pragma("unroll")                                                  \
    for (int j = 0; j < 2; ++j) {                                      \
      bf16x8 pa, pb;                                                   \
      pa[0] = f2bf(ra[2 * j].x);     pa[1] = f2bf(ra[2 * j].y);        \
      pa[2] = f2bf(ra[2 * j].z);     pa[3] = f2bf(ra[2 * j].w);        \
      pa[4] = f2bf(ra[2 * j + 1].x); pa[5] = f2bf(ra[2 * j + 1].y);    \
      pa[6] = f2bf(ra[2 * j + 1].z); pa[7] = f2bf(ra[2 * j + 1].w);    \
      pb[0] = f2bf(rb[2 * j].x);     pb[1] = f2bf(rb[2 * j].y);        \
      pb[2] = f2bf(rb[2 * j].z);     pb[3] = f2bf(rb[2 * j].w);        \
      pb[4] = f2bf(rb[2 * j + 1].x); pb[5] = f2bf(rb[2 * j + 1].y);    \
      pb[6] = f2bf(rb[2 * j + 1].z); pb[7] = f2bf(rb[2 * j + 1].w);    \
      *(bf16x8*)&As[BUF][srow][skq + 8 * j] = pa;                      \
      *(bf16x8*)&Bs[BUF][srow][skq + 8 * j] = pb;                      \
    }                                                                  \
  }

  f32x4 acc[2][2] = {};

#define COMPUTE(BUF)                                                   \
  {                                                                    \
    _Pragma("unroll")                                                  \
    for (int kk = 0; kk < 2; ++kk) {                                   \
      bf16x8 af[2], bff[2];                                            \
      _Pragma("unroll")                                                \
      for (int mi = 0; mi < 2; ++mi)                                   \
        af[mi] = *(const bf16x8*)&As[BUF][wm + (mi << 4) + fr][(kk << 5) + fk]; \
      _Pragma("unroll")                                                \
      for (int ni = 0; ni < 2; ++ni)                                   \
        bff[ni] = *(const bf16x8*)&Bs[BUF][wn + (ni << 4) + fr][(kk << 5) + fk]; \
      _Pragma("unroll")                                                \
      for (int mi = 0; mi < 2; ++mi)                                   \
        _Pragma("unroll")                                              \
        for (int ni = 0; ni < 2; ++ni)                                 \
          acc[mi][ni] = __builtin_amdgcn_mfma_f32_16x16x32_bf16(       \
              af[mi], bff[ni], acc[mi][ni], 0, 0, 0);                  \
    }                                                                  \
  }

  LDCHUNK(0)
  STCHUNK(0)
  __syncthreads();
  LDCHUNK(64) COMPUTE(0) STCHUNK(1) __syncthreads();
  LDCHUNK(128) COMPUTE(1) STCHUNK(0) __syncthreads();
  LDCHUNK(192) COMPUTE(0) STCHUNK(1) __syncthreads();
  COMPUTE(1)

  const float SC = 2.8853900817779268f;  // 2*log2(e)
#pragma unroll
  for (int mi = 0; mi < 2; ++mi) {
#pragma unroll
    for (int ni = 0; ni < 2; ++ni) {
      const int row = m0 + wm + (mi << 4) + ((lane >> 4) << 2);
      const int col = n0 + wn + (ni << 4) + (lane & 15);
#pragma unroll
      for (int r = 0; r < 4; ++r)
        C[(size_t)(row + r) * ldc + col] =
            __builtin_amdgcn_exp2f(acc[mi][ni][r] * SC);
    }
  }
}

// ---------------- Kernel 2a: raw scores ----------------
// Block = 1024 thr = 16 waves; covers 64 e x 32 d. E slice staged in LDS
// transposed [e][h] with 16B-chunk XOR swizzle (chunk ^= row&7): hot loop is
// ONE ds_read_b128 per 4h-group. decE/v remain wave-uniform scalar loads.
// Writes raw -2*acc (vsum cancels in log_softmax). Grid 512 -> 2 blk/CU.

#define PROC1(D4, ACC)                                                 \
  {                                                                    \
    const float m0 = fmaf(E0, (D4).x, 1.0f);                           \
    const float m1 = fmaf(E1, (D4).y, 1.0f);                           \
    const float m2 = fmaf(E2, (D4).z, 1.0f);                           \
    const float m3 = fmaf(E3, (D4).w, 1.0f);                           \
    const float pa = m0 * m1, pb = m2 * m3;                            \
    const float n01 = fmaf(wC.x, m1, wC.y * m0);                       \
    const float n23 = fmaf(wC.z, m3, wC.w * m2);                       \
    const float num = fmaf(n01, pb, n23 * pa);                         \
    ACC = fmaf(num, __builtin_amdgcn_rcpf(pa * pb), ACC);              \
  }

__global__ __launch_bounds__(1024) void scores_k(
    const float* __restrict__ encE, const float* __restrict__ decE,
    const float* __restrict__ v, float* __restrict__ out) {
  const int bid = blockIdx.x;            // 0..511
  // XCD pinning: batch b -> XCDs {2b, 2b+1}
  const int xcd = bid & 7;
  const int b = xcd >> 1;
  const int rem = ((bid >> 3) << 1) | (xcd & 1);   // 0..127 within batch
  const int es = rem & 15;               // e-slice (64 e)
  const int d0 = (rem >> 4) << 5;        // d-group of 32
  const int tid = threadIdx.x;
  const int lane = tid & 63;
  const int wid = __builtin_amdgcn_readfirstlane(tid >> 6);  // 0..15, SGPR

  __shared__ __align__(16) float Es[64 * 256];   // [e-row][h], swizzled chunks

  const int e0 = es << 6;
  const float* egbase = encE + (size_t)b * H_ * ENC_ + e0;

  // ---- stage + transpose + swizzle: 4 float4 loads, 16 ds_writes / thread ----
#pragma unroll
  for (int s = 0; s < 4; ++s) {
    const int fi = (s << 10) + tid;      // 0..4095
    const int h = fi >> 4;               // 0..255
    const int c = fi & 15;               // float4 chunk along e
    const float4 x = *(const float4*)(egbase + (size_t)h * ENC_ + (c << 2));
    const int g = h >> 2, ho = h & 3;
#pragma unroll
    for (int j = 0; j < 4; ++j) {
      const int r = (c << 2) + j;        // e-row 0..63
      Es[(r << 8) + ((g ^ (r & 7)) << 2) + ho] = ((const float*)&x)[j];
    }
  }
  __syncthreads();

  const int d = d0 + (wid << 1);
  const float* dp = decE + (size_t)(b * DEC_ + d) * H_;   // wave-uniform (SGPR)
  float acc0 = 0.0f, acc1 = 0.0f;
  const int ebase = lane << 8;
  const int sw = lane & 7;

#pragma unroll 8
  for (int g = 0; g < 64; ++g) {
    const float4 E4 = *(const float4*)&Es[ebase + ((g ^ sw) << 2)];
    const float E0 = E4.x, E1 = E4.y, E2 = E4.z, E3 = E4.w;
    const int h = g << 2;
    const float4 wC = *(const float4*)(v + h);
    const float4 dA = *(const float4*)(dp + h);
    const float4 dB = *(const float4*)(dp + H_ + h);
    PROC1(dA, acc0)
    PROC1(dB, acc1)
  }

  float* orow = out + (size_t)(b * DEC_ + d) * ENC_ + e0 + lane;
  orow[0] = -2.0f * acc0;
  orow[ENC_] = -2.0f * acc1;
}

// ---------------- Kernel 2b: in-place row log_softmax ----------------
// 1 row (1024 f32) per block, 256 thr x float4.

__global__ __launch_bounds__(256) void lsm_k(float* __restrict__ out) {
  const int row = blockIdx.x;            // 0..1023
  float* p = out + (size_t)row * ENC_;
  const int tid = threadIdx.x;
  const int lane = tid & 63, wid = tid >> 6;

  __shared__ float rm[4], rs[4];

  float4 x = *(const float4*)(p + 4 * tid);

  float m = fmaxf(fmaxf(x.x, x.y), fmaxf(x.z, x.w));
#pragma unroll
  for (int o = 32; o >= 1; o >>= 1) m = fmaxf(m, __shfl_xor(m, o, 64));
  if (lane == 0) rm[wid] = m;
  __syncthreads();
  const float M = fmaxf(fmaxf(rm[0], rm[1]), fmaxf(rm[2], rm[3]));

  const float L2E = 1.4426950408889634f;
  const float LN2 = 0.6931471805599453f;
  float z = __builtin_amdgcn_exp2f((x.x - M) * L2E) +
            __builtin_amdgcn_exp2f((x.y - M) * L2E) +
            __builtin_amdgcn_exp2f((x.z - M) * L2E) +
            __builtin_amdgcn_exp2f((x.w - M) * L2E);
#pragma unroll
  for (int o = 32; o >= 1; o >>= 1) z += __shfl_xor(z, o, 64);
  if (lane == 0) rs[wid] = z;
  __syncthreads();
  const float S = (rs[0] + rs[1]) + (rs[2] + rs[3]);

  const float lse = M + LN2 * __builtin_amdgcn_logf(S);
  x.x -= lse; x.y -= lse; x.z -= lse; x.w -= lse;
  *(float4*)(p + 4 * tid) = x;
}

extern "C" void kernel_launch(void* const* d_in, const int* in_sizes, int n_in,
                              void* d_out, int out_size, void* d_ws, size_t ws_size,
                              hipStream_t stream) {
  const float* xd = (const float*)d_in[0];  // (4,256,256)
  const float* xe = (const float*)d_in[1];  // (4,1024,256)
  const float* w1 = (const float*)d_in[2];  // (256,256)
  const float* w2 = (const float*)d_in[3];  // (256,256)
  const float* v  = (const float*)d_in[4];  // (256,)
  float* out = (float*)d_out;               // (4,256,1024)

  float* encE = (float*)d_ws;                         // 4 MB: [B][H][ENC] = exp2(SC*enc_t)
  float* decE = encE + (size_t)B_ * H_ * ENC_;        // 1 MB: [B][DEC][H] = exp2(SC*dec_t)

  gemm_mfma<<<320, 256, 0, stream>>>(w1, xe, xd, w2, encE, decE);
  scores_k<<<512, 1024, 0, stream>>>(encE, decE, v, out);
  lsm_k<<<B_ * DEC_, 256, 0, stream>>>(out);
}

// Round 11
// 42.041 us; speedup vs baseline: 2.3387x; 1.0493x over previous
//
#include <hip/hip_runtime.h>
#include <hip/hip_bf16.h>

// PointerNetwork: scores[b,d,e] = sum_h v[h]*tanh(dec_t[b,d,h] + enc_t[b,e,h]),
// out = log_softmax(scores, axis=e).  B=4, DEC=256, ENC=1024, H=256, fp32.
//
// tanh(a+b) = 1 - 2/(1 + e^{2a}e^{2b}).
//   K1 (MFMA bf16 + LDS dbuf): encE = exp2(SC*(x_enc.w1));
//       dec side writes decEi INTERLEAVED [dpair][h][2] (d-pair packing) and
//       fills vd[h] = {v,v} (dup table for SGPR-pair packed operands).
//   K2a scores: R10 post-mortem — all memory-side fixes flat; kernel is
//       ISSUE-bound. This round: d-pair packed into float2 -> v_pk_fma_f32
//       (VOP3P, 2 FLOP/lane/inst): 28 VALU -> 14 pk ops per 4h-group.
//   K2b lsm: in-place row log_softmax on d_out.

#define B_ 4
#define DEC_ 256
#define ENC_ 1024
#define H_ 256

using bf16x8 = __attribute__((ext_vector_type(8))) short;
using f32x4 = __attribute__((ext_vector_type(4))) float;
using f2 = __attribute__((ext_vector_type(2))) float;

__device__ inline short f2bf(float f) {
  union { float f; unsigned u; } x; x.f = f;
  return (short)((x.u + 0x8000u) >> 16);   // round-to-nearest
}

// ---------------- Kernel 1: dual GEMM (A . B^T) via MFMA + LDS dbuf ----------------
#define LDK 72   // padded row stride in shorts

__global__ __launch_bounds__(256) void gemm_mfma(
    const float* __restrict__ w1, const float* __restrict__ xe,
    const float* __restrict__ xd, const float* __restrict__ w2,
    const float* __restrict__ v,
    float* __restrict__ encE, float* __restrict__ decEi,
    float* __restrict__ vd) {
  const int blk = blockIdx.x;
  const float* A;
  const float* Bsrc;
  float* C;
  int ldc, m0, n0, decside;
  if (blk < 256) {
    const int b = blk >> 6;
    const int t = blk & 63;            // 4 (h) x 16 (e)
    m0 = (t >> 4) << 6; n0 = (t & 15) << 6;
    A = w1;
    Bsrc = xe + (size_t)b * ENC_ * H_;
    C = encE + (size_t)b * H_ * ENC_;
    ldc = ENC_;
    decside = 0;
  } else {
    const int blk2 = blk - 256;
    const int b = blk2 >> 4;
    const int t = blk2 & 15;           // 4 (d) x 4 (h)
    m0 = (t >> 2) << 6; n0 = (t & 3) << 6;
    A = xd + (size_t)b * DEC_ * H_;
    Bsrc = w2;
    C = decEi + (size_t)b * DEC_ * H_;
    ldc = H_;
    decside = 1;
  }
  const int K = H_;
  const int tid = threadIdx.x;

  // vd dup table (tiny): filled once by block 256
  if (blk == 256) {
    const float x = v[tid & (H_ - 1)];
    if (tid < H_) { vd[2 * tid] = x; vd[2 * tid + 1] = x; }
  }

  const int wave = tid >> 6, lane = tid & 63;
  const int wm = (wave >> 1) << 5, wn = (wave & 1) << 5;
  const int fr = lane & 15;
  const int fk = (lane >> 4) << 3;

  __shared__ short As[2][64][LDK];
  __shared__ short Bs[2][64][LDK];

  const int srow = tid >> 2;
  const int skq = (tid & 3) << 4;
  const float* ag = A + (size_t)(m0 + srow) * K + skq;
  const float* bg = Bsrc + (size_t)(n0 + srow) * K + skq;

  float4 ra[4], rb[4];
#define LDCHUNK(K0)                                                    \
  {                                                                    \
    _Pragma("unroll")                                                  \
    for (int i = 0; i < 4; ++i) {                                      \
      ra[i] = *(const float4*)(ag + (K0) + 4 * i);                     \
      rb[i] = *(const float4*)(bg + (K0) + 4 * i);                     \
    }                                                                  \
  }
#define STCHUNK(BUF)                                                   \
  {                                                                    \
    _Pragma("unroll")                                                  \
    for (int j = 0; j < 2; ++j) {                                      \
      bf16x8 pa, pb;                                                   \
      pa[0] = f2bf(ra[2 * j].x);     pa[1] = f2bf(ra[2 * j].y);        \
      pa[2] = f2bf(ra[2 * j].z);     pa[3] = f2bf(ra[2 * j].w);        \
      pa[4] = f2bf(ra[2 * j + 1].x); pa[5] = f2bf(ra[2 * j + 1].y);    \
      pa[6] = f2bf(ra[2 * j + 1].z); pa[7] = f2bf(ra[2 * j + 1].w);    \
      pb[0] = f2bf(rb[2 * j].x);     pb[1] = f2bf(rb[2 * j].y);        \
      pb[2] = f2bf(rb[2 * j].z);     pb[3] = f2bf(rb[2 * j].w);        \
      pb[4] = f2bf(rb[2 * j + 1].x); pb[5] = f2bf(rb[2 * j + 1].y);    \
      pb[6] = f2bf(rb[2 * j + 1].z); pb[7] = f2bf(rb[2 * j + 1].w);    \
      *(bf16x8*)&As[BUF][srow][skq + 8 * j] = pa;                      \
      *(bf16x8*)&Bs[BUF][srow][skq + 8 * j] = pb;                      \
    }                                                                  \
  }

  f32x4 acc[2][2] = {};

#define COMPUTE(BUF)                                                   \
  {                                                                    \
    _Pragma("unroll")                                                  \
    for (int kk = 0; kk < 2; ++kk) {                                   \
      bf16x8 af[2], bff[2];                                            \
      _Pragma("unroll")                                                \
      for (int mi = 0; mi < 2; ++mi)                                   \
        af[mi] = *(const bf16x8*)&As[BUF][wm + (mi << 4) + fr][(kk << 5) + fk]; \
      _Pragma("unroll")                                                \
      for (int ni = 0; ni < 2; ++ni)                                   \
        bff[ni] = *(const bf16x8*)&Bs[BUF][wn + (ni << 4) + fr][(kk << 5) + fk]; \
      _Pragma("unroll")                                                \
      for (int mi = 0; mi < 2; ++mi)                                   \
        _Pragma("unroll")                                              \
        for (int ni = 0; ni < 2; ++ni)                                 \
          acc[mi][ni] = __builtin_amdgcn_mfma_f32_16x16x32_bf16(       \
              af[mi], bff[ni], acc[mi][ni], 0, 0, 0);                  \
    }                                                                  \
  }

  LDCHUNK(0)
  STCHUNK(0)
  __syncthreads();
  LDCHUNK(64) COMPUTE(0) STCHUNK(1) __syncthreads();
  LDCHUNK(128) COMPUTE(1) STCHUNK(0) __syncthreads();
  LDCHUNK(192) COMPUTE(0) STCHUNK(1) __syncthreads();
  COMPUTE(1)

  const float SC = 2.8853900817779268f;  // 2*log2(e)
#pragma unroll
  for (int mi = 0; mi < 2; ++mi) {
#pragma unroll
    for (int ni = 0; ni < 2; ++ni) {
      const int row = m0 + wm + (mi << 4) + ((lane >> 4) << 2);
      const int col = n0 + wn + (ni << 4) + (lane & 15);
#pragma unroll
      for (int r = 0; r < 4; ++r) {
        const float val = __builtin_amdgcn_exp2f(acc[mi][ni][r] * SC);
        if (decside) {
          // interleaved: [(d>>1)][h][d&1]
          const int rr = row + r;
          C[((size_t)(rr >> 1) * H_ + col) * 2 + (rr & 1)] = val;
        } else {
          C[(size_t)(row + r) * ldc + col] = val;
        }
      }
    }
  }
}

// ---------------- Kernel 2a: raw scores (d-pair packed fp32) ----------------
// Block = 1024 thr = 16 waves; covers 64 e x 32 d. E slice staged in LDS
// transposed [e][h], XOR-swizzled; ONE ds_read_b128 per 4h-group. The two
// d-rows per wave ride the lo/hi halves of float2 -> v_pk_* VOP3P ops.
// Writes raw -2*acc (vsum cancels in log_softmax). Grid 512 -> 2 blk/CU.

__global__ __launch_bounds__(1024) void scores_k(
    const float* __restrict__ encE, const float* __restrict__ decEi,
    const float* __restrict__ vd, float* __restrict__ out) {
  const int bid = blockIdx.x;            // 0..511
  // XCD pinning: batch b -> XCDs {2b, 2b+1}
  const int xcd = bid & 7;
  const int b = xcd >> 1;
  const int rem = ((bid >> 3) << 1) | (xcd & 1);   // 0..127 within batch
  const int es = rem & 15;               // e-slice (64 e)
  const int d0 = (rem >> 4) << 5;        // d-group of 32
  const int tid = threadIdx.x;
  const int lane = tid & 63;
  const int wid = __builtin_amdgcn_readfirstlane(tid >> 6);  // 0..15, SGPR

  __shared__ __align__(16) float Es[64 * 256];   // [e-row][h], swizzled chunks

  const int e0 = es << 6;
  const float* egbase = encE + (size_t)b * H_ * ENC_ + e0;

  // ---- stage + transpose + swizzle: 4 float4 loads, 16 ds_writes / thread ----
#pragma unroll
  for (int s = 0; s < 4; ++s) {
    const int fi = (s << 10) + tid;      // 0..4095
    const int h = fi >> 4;               // 0..255
    const int c = fi & 15;               // float4 chunk along e
    const float4 x = *(const float4*)(egbase + (size_t)h * ENC_ + (c << 2));
    const int g = h >> 2, ho = h & 3;
#pragma unroll
    for (int j = 0; j < 4; ++j) {
      const int r = (c << 2) + j;        // e-row 0..63
      Es[(r << 8) + ((g ^ (r & 7)) << 2) + ho] = ((const float*)&x)[j];
    }
  }
  __syncthreads();

  const int dpair = (d0 >> 1) + wid;     // d = 2*dpair, 2*dpair+1
  const float* dpi = decEi + (size_t)b * DEC_ * H_ + (size_t)dpair * (2 * H_);
  const int ebase = lane << 8;
  const int sw = lane & 7;

  const f2 one = {1.0f, 1.0f};
  f2 acc = {0.0f, 0.0f};

#pragma unroll 4
  for (int g = 0; g < 64; ++g) {
    const float4 E4 = *(const float4*)&Es[ebase + ((g ^ sw) << 2)];
    const f2* dq = (const f2*)(dpi + (g << 3));   // {dA,dB} for h=4g..4g+3
    const f2* wq = (const f2*)(vd + (g << 3));    // {v,v} dup pairs
    const f2 e0v = {E4.x, E4.x};
    const f2 e1v = {E4.y, E4.y};
    const f2 e2v = {E4.z, E4.z};
    const f2 e3v = {E4.w, E4.w};
    const f2 m0 = e0v * dq[0] + one;
    const f2 m1 = e1v * dq[1] + one;
    const f2 m2 = e2v * dq[2] + one;
    const f2 m3 = e3v * dq[3] + one;
    const f2 pa = m0 * m1, pb = m2 * m3;
    const f2 n01 = wq[0] * m1 + wq[1] * m0;
    const f2 n23 = wq[2] * m3 + wq[3] * m2;
    const f2 num = n01 * pb + n23 * pa;
    const f2 den = pa * pb;
    const f2 r = {__builtin_amdgcn_rcpf(den.x), __builtin_amdgcn_rcpf(den.y)};
    acc = num * r + acc;
  }

  const int d = dpair << 1;
  float* orow = out + (size_t)(b * DEC_ + d) * ENC_ + e0 + lane;
  orow[0] = -2.0f * acc.x;
  orow[ENC_] = -2.0f * acc.y;
}

// ---------------- Kernel 2b: in-place row log_softmax ----------------
// 1 row (1024 f32) per block, 256 thr x float4.

__global__ __launch_bounds__(256) void lsm_k(float* __restrict__ out) {
  const int row = blockIdx.x;            // 0..1023
  float* p = out + (size_t)row * ENC_;
  const int tid = threadIdx.x;
  const int lane = tid & 63, wid = tid >> 6;

  __shared__ float rm[4], rs[4];

  float4 x = *(const float4*)(p + 4 * tid);

  float m = fmaxf(fmaxf(x.x, x.y), fmaxf(x.z, x.w));
#pragma unroll
  for (int o = 32; o >= 1; o >>= 1) m = fmaxf(m, __shfl_xor(m, o, 64));
  if (lane == 0) rm[wid] = m;
  __syncthreads();
  const float M = fmaxf(fmaxf(rm[0], rm[1]), fmaxf(rm[2], rm[3]));

  const float L2E = 1.4426950408889634f;
  const float LN2 = 0.6931471805599453f;
  float z = __builtin_amdgcn_exp2f((x.x - M) * L2E) +
            __builtin_amdgcn_exp2f((x.y - M) * L2E) +
            __builtin_amdgcn_exp2f((x.z - M) * L2E) +
            __builtin_amdgcn_exp2f((x.w - M) * L2E);
#pragma unroll
  for (int o = 32; o >= 1; o >>= 1) z += __shfl_xor(z, o, 64);
  if (lane == 0) rs[wid] = z;
  __syncthreads();
  const float S = (rs[0] + rs[1]) + (rs[2] + rs[3]);

  const float lse = M + LN2 * __builtin_amdgcn_logf(S);
  x.x -= lse; x.y -= lse; x.z -= lse; x.w -= lse;
  *(float4*)(p + 4 * tid) = x;
}

extern "C" void kernel_launch(void* const* d_in, const int* in_sizes, int n_in,
                              void* d_out, int out_size, void* d_ws, size_t ws_size,
                              hipStream_t stream) {
  const float* xd = (const float*)d_in[0];  // (4,256,256)
  const float* xe = (const float*)d_in[1];  // (4,1024,256)
  const float* w1 = (const float*)d_in[2];  // (256,256)
  const float* w2 = (const float*)d_in[3];  // (256,256)
  const float* v  = (const float*)d_in[4];  // (256,)
  float* out = (float*)d_out;               // (4,256,1024)

  float* encE = (float*)d_ws;                          // 4 MB: [B][H][ENC]
  float* decEi = encE + (size_t)B_ * H_ * ENC_;        // 1 MB: [B][dpair][H][2]
  float* vd = decEi + (size_t)B_ * DEC_ * H_;          // 2 KB: {v,v} dup

  gemm_mfma<<<320, 256, 0, stream>>>(w1, xe, xd, w2, v, encE, decEi, vd);
  scores_k<<<512, 1024, 0, stream>>>(encE, decEi, vd, out);
  lsm_k<<<B_ * DEC_, 256, 0, stream>>>(out);
}